// Round 1
// baseline (1201.332 us; speedup 1.0000x reference)
//
#include <hip/hip_runtime.h>
#include <hip/hip_bf16.h>
#include <math.h>

#define ALPHA 0.2f
#define N_NODES 50000
#define N_EDGES 800000
#define HEADS 8
#define DH 64
#define HD 512   // HEADS*DH

// ---------------------------------------------------------------------------
// row_ptr[n] = lower_bound(edge_src, n)  (edge_src is sorted ascending)
// ---------------------------------------------------------------------------
__global__ void build_rowptr(const int* __restrict__ src, int E, int n_nodes,
                             int* __restrict__ row_ptr) {
    int n = blockIdx.x * blockDim.x + threadIdx.x;
    if (n > n_nodes) return;
    int lo = 0, hi = E;
    while (lo < hi) {
        int mid = (lo + hi) >> 1;
        if (src[mid] < n) lo = mid + 1; else hi = mid;
    }
    row_ptr[n] = lo;
}

// ---------------------------------------------------------------------------
// C[M,N] = A[M,K] @ B  (+bias), B indexed head-blocked:
//   B(f, n) = B[(n>>6)*K*64 + f*64 + (n&63)]
// (matches W[h][f][d] layout; for N=64 it degenerates to plain [K,64])
// Tiled f32: BM=BN=64, BK=16, 256 threads, 4x4 micro-tile.
// ---------------------------------------------------------------------------
#define BM 64
#define BN 64
#define BK 16

__global__ __launch_bounds__(256) void gemm_hb(
    const float* __restrict__ A, const float* __restrict__ B,
    const float* __restrict__ bias, float* __restrict__ C,
    int M, int K, int N)
{
    __shared__ float As[BK][BM];
    __shared__ float Bs[BK][BN];

    const int bm = blockIdx.x * BM;
    const int bn = blockIdx.y * BN;
    const int tid = threadIdx.x;
    const int tx = tid & 15;       // n-dir
    const int ty = tid >> 4;       // m-dir

    float acc[4][4] = {};

    const int ar = tid >> 2;            // A row within tile, 0..63
    const int ac = (tid & 3) * 4;       // A col group
    const int bnn = tid & 63;           // B col within tile
    const int gh = (bn + bnn) >> 6;     // head index
    const int gd = (bn + bnn) & 63;     // d index
    const size_t bhead = (size_t)gh * K * 64 + gd;

    for (int k0 = 0; k0 < K; k0 += BK) {
        // stage A (transposed into LDS)
        {
            int gr = bm + ar;
            float4 v = make_float4(0.f, 0.f, 0.f, 0.f);
            if (gr < M)
                v = *reinterpret_cast<const float4*>(&A[(size_t)gr * K + k0 + ac]);
            As[ac + 0][ar] = v.x;
            As[ac + 1][ar] = v.y;
            As[ac + 2][ar] = v.z;
            As[ac + 3][ar] = v.w;
        }
        // stage B
        {
            #pragma unroll
            for (int it = 0; it < 4; ++it) {
                int fl = (tid >> 6) + it * 4;          // 0..15
                Bs[fl][bnn] = B[bhead + (size_t)(k0 + fl) * 64];
            }
        }
        __syncthreads();
        #pragma unroll
        for (int kk = 0; kk < BK; ++kk) {
            float4 av = *reinterpret_cast<const float4*>(&As[kk][ty * 4]);
            float4 bv = *reinterpret_cast<const float4*>(&Bs[kk][tx * 4]);
            float a0 = av.x, a1 = av.y, a2 = av.z, a3 = av.w;
            float b0 = bv.x, b1 = bv.y, b2 = bv.z, b3 = bv.w;
            acc[0][0] += a0 * b0; acc[0][1] += a0 * b1; acc[0][2] += a0 * b2; acc[0][3] += a0 * b3;
            acc[1][0] += a1 * b0; acc[1][1] += a1 * b1; acc[1][2] += a1 * b2; acc[1][3] += a1 * b3;
            acc[2][0] += a2 * b0; acc[2][1] += a2 * b1; acc[2][2] += a2 * b2; acc[2][3] += a2 * b3;
            acc[3][0] += a3 * b0; acc[3][1] += a3 * b1; acc[3][2] += a3 * b2; acc[3][3] += a3 * b3;
        }
        __syncthreads();
    }

    #pragma unroll
    for (int i = 0; i < 4; ++i) {
        int gr = bm + ty * 4 + i;
        if (gr >= M) continue;
        #pragma unroll
        for (int j = 0; j < 4; ++j) {
            int gc = bn + tx * 4 + j;
            float v = acc[i][j];
            if (bias) v += bias[gc];
            C[(size_t)gr * N + gc] = v;
        }
    }
}

// ---------------------------------------------------------------------------
// f1[n,h] = sum_d Wh[n,h*64+d]*a_s[h,d];  f2 likewise with a_d
// one wave (64 lanes) per node
// ---------------------------------------------------------------------------
__global__ __launch_bounds__(64) void node_scores(
    const float* __restrict__ Wh, const float* __restrict__ a_s,
    const float* __restrict__ a_d, float* __restrict__ f1,
    float* __restrict__ f2, int n_nodes)
{
    int n = blockIdx.x;
    if (n >= n_nodes) return;
    int lane = threadIdx.x;
    #pragma unroll
    for (int h = 0; h < HEADS; ++h) {
        float w = Wh[(size_t)n * HD + h * DH + lane];
        float v1 = w * a_s[h * DH + lane];
        float v2 = w * a_d[h * DH + lane];
        #pragma unroll
        for (int m = 32; m; m >>= 1) {
            v1 += __shfl_xor(v1, m);
            v2 += __shfl_xor(v2, m);
        }
        if (lane == 0) {
            f1[(size_t)n * HEADS + h] = v1;
            f2[(size_t)n * HEADS + h] = v2;
        }
    }
}

// ---------------------------------------------------------------------------
// Fused per-node: LeakyReLU scores -> segment softmax -> SpMM -> ELU
// One block (256 threads) per node. Edges of node n: [row_ptr[n], row_ptr[n+1])
// ---------------------------------------------------------------------------
__global__ __launch_bounds__(256) void gat_node(
    const float* __restrict__ Wh, const float* __restrict__ f1,
    const float* __restrict__ f2, const int* __restrict__ row_ptr,
    const int* __restrict__ dst, float* __restrict__ out, int n_nodes)
{
    __shared__ float s_f1[HEADS];
    __shared__ float s_m[HEADS];
    __shared__ float s_inv[HEADS];
    __shared__ float red[256];
    __shared__ int   s_dst[64];
    __shared__ float s_p[64][HEADS];

    const int n = blockIdx.x;
    if (n >= n_nodes) return;
    const int tid = threadIdx.x;
    const int lo = row_ptr[n], hi = row_ptr[n + 1];
    const int deg = hi - lo;

    const int h_out = tid >> 5;       // 0..7
    const int d0 = tid & 31;          // covers d0 and d0+32
    float acc0 = 0.f, acc1 = 0.f;

    if (deg > 0) {
        if (tid < HEADS) s_f1[tid] = f1[(size_t)n * HEADS + tid];
        __syncthreads();
        const int myh = tid & 7;
        const float f1h = s_f1[myh];

        // pass 1: per-head max of LeakyReLU(f1[n]+f2[dst])
        float lmax = -INFINITY;
        for (int idx = tid; idx < deg * HEADS; idx += 256) {
            int j = idx >> 3;
            int dn = dst[lo + j];
            float e = f1h + f2[(size_t)dn * HEADS + myh];
            e = e > 0.f ? e : ALPHA * e;
            lmax = fmaxf(lmax, e);
        }
        red[tid] = lmax;
        __syncthreads();
        for (int s = 128; s >= 8; s >>= 1) {
            if (tid < s) red[tid] = fmaxf(red[tid], red[tid + s]);
            __syncthreads();
        }
        if (tid < HEADS) s_m[tid] = red[tid];
        __syncthreads();
        const float mh = s_m[myh];

        // pass 2: per-head sum of exp
        float lsum = 0.f;
        for (int idx = tid; idx < deg * HEADS; idx += 256) {
            int j = idx >> 3;
            int dn = dst[lo + j];
            float e = f1h + f2[(size_t)dn * HEADS + myh];
            e = e > 0.f ? e : ALPHA * e;
            lsum += __expf(e - mh);
        }
        red[tid] = lsum;
        __syncthreads();
        for (int s = 128; s >= 8; s >>= 1) {
            if (tid < s) red[tid] += red[tid + s];
            __syncthreads();
        }
        if (tid < HEADS) s_inv[tid] = 1.f / fmaxf(red[tid], 1e-16f);
        __syncthreads();

        // pass 3: chunks of 64 edges: compute att into LDS, then accumulate
        for (int c0 = 0; c0 < deg; c0 += 64) {
            int cn = min(64, deg - c0);
            if (tid < cn) s_dst[tid] = dst[lo + c0 + tid];
            __syncthreads();
            for (int idx = tid; idx < cn * HEADS; idx += 256) {
                int j = idx >> 3;
                int hh = idx & 7;
                int dn = s_dst[j];
                float e = s_f1[hh] + f2[(size_t)dn * HEADS + hh];
                e = e > 0.f ? e : ALPHA * e;
                s_p[j][hh] = __expf(e - s_m[hh]) * s_inv[hh];
            }
            __syncthreads();
            for (int j = 0; j < cn; ++j) {
                float p = s_p[j][h_out];
                const float* w = &Wh[(size_t)s_dst[j] * HD + h_out * DH];
                acc0 += p * w[d0];
                acc1 += p * w[d0 + 32];
            }
            __syncthreads();
        }
    }

    // ELU epilogue
    float o0 = acc0 > 0.f ? acc0 : expm1f(acc0);
    float o1 = acc1 > 0.f ? acc1 : expm1f(acc1);
    out[(size_t)n * HD + h_out * DH + d0] = o0;
    out[(size_t)n * HD + h_out * DH + d0 + 32] = o1;
}

// ---------------------------------------------------------------------------
extern "C" void kernel_launch(void* const* d_in, const int* in_sizes, int n_in,
                              void* d_out, int out_size, void* d_ws, size_t ws_size,
                              hipStream_t stream) {
    const float* x      = (const float*)d_in[0];
    const int*   e_src  = (const int*)d_in[1];
    const int*   e_dst  = (const int*)d_in[2];
    const float* W1     = (const float*)d_in[3];
    const float* a_src1 = (const float*)d_in[4];
    const float* a_dst1 = (const float*)d_in[5];
    const float* W2     = (const float*)d_in[6];
    const float* a_src2 = (const float*)d_in[7];
    const float* a_dst2 = (const float*)d_in[8];
    const float* lin_W  = (const float*)d_in[9];
    const float* lin_b  = (const float*)d_in[10];
    float* outp = (float*)d_out;

    // workspace: bufA (Wh) | bufB (h) | f1 | f2 | row_ptr   (~208 MB)
    float* bufA = (float*)d_ws;
    float* bufB = bufA + (size_t)N_NODES * HD;
    float* f1   = bufB + (size_t)N_NODES * HD;
    float* f2   = f1 + (size_t)N_NODES * HEADS;
    int* rowptr = (int*)(f2 + (size_t)N_NODES * HEADS);

    build_rowptr<<<(N_NODES + 256) / 256, 256, 0, stream>>>(e_src, N_EDGES, N_NODES, rowptr);

    dim3 g1((N_NODES + BM - 1) / BM, HD / BN);
    // layer 1: Wh1 = x @ W1
    gemm_hb<<<g1, 256, 0, stream>>>(x, W1, nullptr, bufA, N_NODES, 256, HD);
    node_scores<<<N_NODES, 64, 0, stream>>>(bufA, a_src1, a_dst1, f1, f2, N_NODES);
    gat_node<<<N_NODES, 256, 0, stream>>>(bufA, f1, f2, rowptr, e_dst, bufB, N_NODES);

    // layer 2: Wh2 = h1 @ W2
    gemm_hb<<<g1, 256, 0, stream>>>(bufB, W2, nullptr, bufA, N_NODES, HD, HD);
    node_scores<<<N_NODES, 64, 0, stream>>>(bufA, a_src2, a_dst2, f1, f2, N_NODES);
    gat_node<<<N_NODES, 256, 0, stream>>>(bufA, f1, f2, rowptr, e_dst, bufB, N_NODES);

    // output: h2 @ lin_W + lin_b
    dim3 g3((N_NODES + BM - 1) / BM, 1);
    gemm_hb<<<g3, 256, 0, stream>>>(bufB, lin_W, lin_b, outp, N_NODES, HD, 64);
}

// Round 2
// 853.966 us; speedup vs baseline: 1.4068x; 1.4068x over previous
//
#include <hip/hip_runtime.h>
#include <hip/hip_bf16.h>
#include <math.h>

#define ALPHA 0.2f
#define N_NODES 50000
#define N_EDGES 800000
#define HEADS 8
#define DH 64
#define HD 512   // HEADS*DH

typedef __attribute__((ext_vector_type(8))) short short8v;
typedef __attribute__((ext_vector_type(4))) float float4v;

// round-to-nearest-even f32 -> bf16 bits
__device__ __forceinline__ unsigned short f2bf(float f) {
    unsigned int u = __float_as_uint(f);
    unsigned int r = (u + 0x7fffu + ((u >> 16) & 1u)) >> 16;
    return (unsigned short)r;
}
__device__ __forceinline__ float bf2f(unsigned short h) {
    return __uint_as_float(((unsigned int)h) << 16);
}

// ---------------------------------------------------------------------------
// row_ptr[n] = lower_bound(edge_src, n)  (edge_src is sorted ascending)
// ---------------------------------------------------------------------------
__global__ void build_rowptr(const int* __restrict__ src, int E, int n_nodes,
                             int* __restrict__ row_ptr) {
    int n = blockIdx.x * blockDim.x + threadIdx.x;
    if (n > n_nodes) return;
    int lo = 0, hi = E;
    while (lo < hi) {
        int mid = (lo + hi) >> 1;
        if (src[mid] < n) lo = mid + 1; else hi = mid;
    }
    row_ptr[n] = lo;
}

// ---------------------------------------------------------------------------
// W[h][f][d]  ->  Bt[(h*64+d)][F]   (f32, tiny)
// ---------------------------------------------------------------------------
__global__ void transpose_w(const float* __restrict__ in, float* __restrict__ out,
                            int F, int total) {
    int idx = blockIdx.x * 256 + threadIdx.x;
    if (idx >= total) return;
    int d = idx & 63;
    int f = (idx >> 6) % F;
    int h = idx / (F << 6);
    out[(size_t)((h << 6) + d) * F + f] = in[idx];
}

// ---------------------------------------------------------------------------
// C[M,N] = A[M,K] @ Bt^T (+bias), fp32 in/out, split-bf16 MFMA internally.
// Bt is [N][K] row-major (pre-transposed weights).
// Tile 128x64, BK=32, 256 threads = 4 waves (2x2), mfma_f32_16x16x32_bf16.
// 3-product split: AhiBhi + AhiBlo + AloBhi  (~fp32 accuracy).
// ---------------------------------------------------------------------------
__global__ __launch_bounds__(256) void gemm_mfma_split(
    const float* __restrict__ A, const float* __restrict__ Bt,
    const float* __restrict__ bias, float* __restrict__ C,
    int M, int K, int N)
{
    __shared__ unsigned short AsH[128][32];
    __shared__ unsigned short AsL[128][32];
    __shared__ unsigned short BsH[64][32];
    __shared__ unsigned short BsL[64][32];

    const int tid = threadIdx.x;
    const int bm = blockIdx.x * 128;
    const int bn = blockIdx.y * 64;

    // staging coords
    const int sr = tid >> 2;          // 0..63
    const int sk = (tid & 3) * 8;     // 0,8,16,24

    // wave/fragment coords
    const int wid = tid >> 6;
    const int lane = tid & 63;
    const int wr = (wid >> 1) * 64;   // wave row offset (0/64)
    const int wc = (wid & 1) * 32;    // wave col offset (0/32)
    const int fr = lane & 15;
    const int fk = (lane >> 4) * 8;

    float4v acc[4][2];
    #pragma unroll
    for (int m = 0; m < 4; ++m)
        #pragma unroll
        for (int n = 0; n < 2; ++n)
            acc[m][n] = (float4v){0.f, 0.f, 0.f, 0.f};

    for (int k0 = 0; k0 < K; k0 += 32) {
        // ---- stage A (128x32) as hi/lo bf16 ----
        #pragma unroll
        for (int rr = 0; rr < 2; ++rr) {
            int r = sr + rr * 64;
            int gr = bm + r;
            float4 v0 = make_float4(0.f, 0.f, 0.f, 0.f);
            float4 v1 = make_float4(0.f, 0.f, 0.f, 0.f);
            if (gr < M) {
                const float* p = &A[(size_t)gr * K + k0 + sk];
                v0 = *reinterpret_cast<const float4*>(p);
                v1 = *reinterpret_cast<const float4*>(p + 4);
            }
            float vv[8] = {v0.x, v0.y, v0.z, v0.w, v1.x, v1.y, v1.z, v1.w};
            short8v h8, l8;
            #pragma unroll
            for (int j = 0; j < 8; ++j) {
                unsigned short hb = f2bf(vv[j]);
                h8[j] = (short)hb;
                l8[j] = (short)f2bf(vv[j] - bf2f(hb));
            }
            *reinterpret_cast<short8v*>(&AsH[r][sk]) = h8;
            *reinterpret_cast<short8v*>(&AsL[r][sk]) = l8;
        }
        // ---- stage B (64x32, stored [col][k]) ----
        {
            const float* p = &Bt[(size_t)(bn + sr) * K + k0 + sk];
            float4 v0 = *reinterpret_cast<const float4*>(p);
            float4 v1 = *reinterpret_cast<const float4*>(p + 4);
            float vv[8] = {v0.x, v0.y, v0.z, v0.w, v1.x, v1.y, v1.z, v1.w};
            short8v h8, l8;
            #pragma unroll
            for (int j = 0; j < 8; ++j) {
                unsigned short hb = f2bf(vv[j]);
                h8[j] = (short)hb;
                l8[j] = (short)f2bf(vv[j] - bf2f(hb));
            }
            *reinterpret_cast<short8v*>(&BsH[sr][sk]) = h8;
            *reinterpret_cast<short8v*>(&BsL[sr][sk]) = l8;
        }
        __syncthreads();

        // ---- fragments + MFMA ----
        short8v aH[4], aL[4], bH[2], bL[2];
        #pragma unroll
        for (int m = 0; m < 4; ++m) {
            aH[m] = *reinterpret_cast<const short8v*>(&AsH[wr + m * 16 + fr][fk]);
            aL[m] = *reinterpret_cast<const short8v*>(&AsL[wr + m * 16 + fr][fk]);
        }
        #pragma unroll
        for (int n = 0; n < 2; ++n) {
            bH[n] = *reinterpret_cast<const short8v*>(&BsH[wc + n * 16 + fr][fk]);
            bL[n] = *reinterpret_cast<const short8v*>(&BsL[wc + n * 16 + fr][fk]);
        }
        #pragma unroll
        for (int m = 0; m < 4; ++m) {
            #pragma unroll
            for (int n = 0; n < 2; ++n) {
                acc[m][n] = __builtin_amdgcn_mfma_f32_16x16x32_bf16(aH[m], bH[n], acc[m][n], 0, 0, 0);
                acc[m][n] = __builtin_amdgcn_mfma_f32_16x16x32_bf16(aH[m], bL[n], acc[m][n], 0, 0, 0);
                acc[m][n] = __builtin_amdgcn_mfma_f32_16x16x32_bf16(aL[m], bH[n], acc[m][n], 0, 0, 0);
            }
        }
        __syncthreads();
    }

    // ---- epilogue: C/D layout col=lane&15, row=(lane>>4)*4+r ----
    #pragma unroll
    for (int m = 0; m < 4; ++m) {
        int row = bm + wr + m * 16 + (lane >> 4) * 4;
        #pragma unroll
        for (int n = 0; n < 2; ++n) {
            int col = bn + wc + n * 16 + fr;
            float b = bias ? bias[col] : 0.f;
            #pragma unroll
            for (int r = 0; r < 4; ++r) {
                if (row + r < M)
                    C[(size_t)(row + r) * N + col] = acc[m][n][r] + b;
            }
        }
    }
}

// ---------------------------------------------------------------------------
// f1[n,h] = sum_d Wh[n,h*64+d]*a_s[h,d];  f2 likewise with a_d
// ---------------------------------------------------------------------------
__global__ __launch_bounds__(64) void node_scores(
    const float* __restrict__ Wh, const float* __restrict__ a_s,
    const float* __restrict__ a_d, float* __restrict__ f1,
    float* __restrict__ f2, int n_nodes)
{
    int n = blockIdx.x;
    if (n >= n_nodes) return;
    int lane = threadIdx.x;
    #pragma unroll
    for (int h = 0; h < HEADS; ++h) {
        float w = Wh[(size_t)n * HD + h * DH + lane];
        float v1 = w * a_s[h * DH + lane];
        float v2 = w * a_d[h * DH + lane];
        #pragma unroll
        for (int m = 32; m; m >>= 1) {
            v1 += __shfl_xor(v1, m);
            v2 += __shfl_xor(v2, m);
        }
        if (lane == 0) {
            f1[(size_t)n * HEADS + h] = v1;
            f2[(size_t)n * HEADS + h] = v2;
        }
    }
}

// ---------------------------------------------------------------------------
// Fused per-node: LeakyReLU scores -> segment softmax -> SpMM -> ELU
// ---------------------------------------------------------------------------
__global__ __launch_bounds__(256) void gat_node(
    const float* __restrict__ Wh, const float* __restrict__ f1,
    const float* __restrict__ f2, const int* __restrict__ row_ptr,
    const int* __restrict__ dst, float* __restrict__ out, int n_nodes)
{
    __shared__ float s_f1[HEADS];
    __shared__ float s_m[HEADS];
    __shared__ float s_inv[HEADS];
    __shared__ float red[256];
    __shared__ int   s_dst[64];
    __shared__ float s_p[64][HEADS];

    const int n = blockIdx.x;
    if (n >= n_nodes) return;
    const int tid = threadIdx.x;
    const int lo = row_ptr[n], hi = row_ptr[n + 1];
    const int deg = hi - lo;

    const int h_out = tid >> 5;       // 0..7
    const int d0 = tid & 31;
    float acc0 = 0.f, acc1 = 0.f;

    if (deg > 0) {
        if (tid < HEADS) s_f1[tid] = f1[(size_t)n * HEADS + tid];
        __syncthreads();
        const int myh = tid & 7;
        const float f1h = s_f1[myh];

        float lmax = -INFINITY;
        for (int idx = tid; idx < deg * HEADS; idx += 256) {
            int j = idx >> 3;
            int dn = dst[lo + j];
            float e = f1h + f2[(size_t)dn * HEADS + myh];
            e = e > 0.f ? e : ALPHA * e;
            lmax = fmaxf(lmax, e);
        }
        red[tid] = lmax;
        __syncthreads();
        for (int s = 128; s >= 8; s >>= 1) {
            if (tid < s) red[tid] = fmaxf(red[tid], red[tid + s]);
            __syncthreads();
        }
        if (tid < HEADS) s_m[tid] = red[tid];
        __syncthreads();
        const float mh = s_m[myh];

        float lsum = 0.f;
        for (int idx = tid; idx < deg * HEADS; idx += 256) {
            int j = idx >> 3;
            int dn = dst[lo + j];
            float e = f1h + f2[(size_t)dn * HEADS + myh];
            e = e > 0.f ? e : ALPHA * e;
            lsum += __expf(e - mh);
        }
        red[tid] = lsum;
        __syncthreads();
        for (int s = 128; s >= 8; s >>= 1) {
            if (tid < s) red[tid] += red[tid + s];
            __syncthreads();
        }
        if (tid < HEADS) s_inv[tid] = 1.f / fmaxf(red[tid], 1e-16f);
        __syncthreads();

        for (int c0 = 0; c0 < deg; c0 += 64) {
            int cn = min(64, deg - c0);
            if (tid < cn) s_dst[tid] = dst[lo + c0 + tid];
            __syncthreads();
            for (int idx = tid; idx < cn * HEADS; idx += 256) {
                int j = idx >> 3;
                int hh = idx & 7;
                int dn = s_dst[j];
                float e = s_f1[hh] + f2[(size_t)dn * HEADS + hh];
                e = e > 0.f ? e : ALPHA * e;
                s_p[j][hh] = __expf(e - s_m[hh]) * s_inv[hh];
            }
            __syncthreads();
            for (int j = 0; j < cn; ++j) {
                float p = s_p[j][h_out];
                const float* w = &Wh[(size_t)s_dst[j] * HD + h_out * DH];
                acc0 += p * w[d0];
                acc1 += p * w[d0 + 32];
            }
            __syncthreads();
        }
    }

    float o0 = acc0 > 0.f ? acc0 : expm1f(acc0);
    float o1 = acc1 > 0.f ? acc1 : expm1f(acc1);
    out[(size_t)n * HD + h_out * DH + d0] = o0;
    out[(size_t)n * HD + h_out * DH + d0 + 32] = o1;
}

// ---------------------------------------------------------------------------
extern "C" void kernel_launch(void* const* d_in, const int* in_sizes, int n_in,
                              void* d_out, int out_size, void* d_ws, size_t ws_size,
                              hipStream_t stream) {
    const float* x      = (const float*)d_in[0];
    const int*   e_src  = (const int*)d_in[1];
    const int*   e_dst  = (const int*)d_in[2];
    const float* W1     = (const float*)d_in[3];
    const float* a_src1 = (const float*)d_in[4];
    const float* a_dst1 = (const float*)d_in[5];
    const float* W2     = (const float*)d_in[6];
    const float* a_src2 = (const float*)d_in[7];
    const float* a_dst2 = (const float*)d_in[8];
    const float* lin_W  = (const float*)d_in[9];
    const float* lin_b  = (const float*)d_in[10];
    float* outp = (float*)d_out;

    // workspace: Wh (f32) | h (f32) | f1 | f2 | rowptr | BtW1 | BtW2 | BtLin
    float* bufWh = (float*)d_ws;
    float* bufH  = bufWh + (size_t)N_NODES * HD;
    float* f1    = bufH + (size_t)N_NODES * HD;
    float* f2    = f1 + (size_t)N_NODES * HEADS;
    int* rowptr  = (int*)(f2 + (size_t)N_NODES * HEADS);
    float* BtW1  = (float*)(rowptr + N_NODES + 64);
    float* BtW2  = BtW1 + (size_t)HD * 256;
    float* BtLin = BtW2 + (size_t)HD * HD;

    build_rowptr<<<(N_NODES + 256) / 256, 256, 0, stream>>>(e_src, N_EDGES, N_NODES, rowptr);
    transpose_w<<<(HEADS * 256 * DH + 255) / 256, 256, 0, stream>>>(W1, BtW1, 256, HEADS * 256 * DH);
    transpose_w<<<(HEADS * HD * DH + 255) / 256, 256, 0, stream>>>(W2, BtW2, HD, HEADS * HD * DH);
    transpose_w<<<(HD * 64 + 255) / 256, 256, 0, stream>>>(lin_W, BtLin, HD, HD * 64);

    dim3 g1((N_NODES + 127) / 128, HD / 64);
    // layer 1
    gemm_mfma_split<<<g1, 256, 0, stream>>>(x, BtW1, nullptr, bufWh, N_NODES, 256, HD);
    node_scores<<<N_NODES, 64, 0, stream>>>(bufWh, a_src1, a_dst1, f1, f2, N_NODES);
    gat_node<<<N_NODES, 256, 0, stream>>>(bufWh, f1, f2, rowptr, e_dst, bufH, N_NODES);

    // layer 2
    gemm_mfma_split<<<g1, 256, 0, stream>>>(bufH, BtW2, nullptr, bufWh, N_NODES, HD, HD);
    node_scores<<<N_NODES, 64, 0, stream>>>(bufWh, a_src2, a_dst2, f1, f2, N_NODES);
    gat_node<<<N_NODES, 256, 0, stream>>>(bufWh, f1, f2, rowptr, e_dst, bufH, N_NODES);

    // output
    dim3 g3((N_NODES + 127) / 128, 1);
    gemm_mfma_split<<<g3, 256, 0, stream>>>(bufH, BtLin, lin_b, outp, N_NODES, HD, 64);
}

// Round 3
// 689.187 us; speedup vs baseline: 1.7431x; 1.2391x over previous
//
#include <hip/hip_runtime.h>
#include <hip/hip_bf16.h>
#include <math.h>

#define ALPHA 0.2f
#define N_NODES 50000
#define N_EDGES 800000
#define HEADS 8
#define DH 64
#define HD 512   // HEADS*DH

typedef __attribute__((ext_vector_type(8))) short short8v;
typedef __attribute__((ext_vector_type(4))) float float4v;

// round-to-nearest-even f32 -> bf16 bits
__device__ __forceinline__ unsigned short f2bf(float f) {
    unsigned int u = __float_as_uint(f);
    unsigned int r = (u + 0x7fffu + ((u >> 16) & 1u)) >> 16;
    return (unsigned short)r;
}
__device__ __forceinline__ float bf2f(unsigned short h) {
    return __uint_as_float(((unsigned int)h) << 16);
}

// ---------------------------------------------------------------------------
// row_ptr[n] = lower_bound(edge_src, n)  (edge_src is sorted ascending)
// ---------------------------------------------------------------------------
__global__ void build_rowptr(const int* __restrict__ src, int E, int n_nodes,
                             int* __restrict__ row_ptr) {
    int n = blockIdx.x * blockDim.x + threadIdx.x;
    if (n > n_nodes) return;
    int lo = 0, hi = E;
    while (lo < hi) {
        int mid = (lo + hi) >> 1;
        if (src[mid] < n) lo = mid + 1; else hi = mid;
    }
    row_ptr[n] = lo;
}

// ---------------------------------------------------------------------------
// W[h][f][d]  ->  Bt[(h*64+d)][F]   (f32, tiny)
// ---------------------------------------------------------------------------
__global__ void transpose_w(const float* __restrict__ in, float* __restrict__ out,
                            int F, int total) {
    int idx = blockIdx.x * 256 + threadIdx.x;
    if (idx >= total) return;
    int d = idx & 63;
    int f = (idx >> 6) % F;
    int h = idx / (F << 6);
    out[(size_t)((h << 6) + d) * F + f] = in[idx];
}

// ---------------------------------------------------------------------------
// Split-bf16 MFMA GEMM, fp32 A in, fp32-accurate.
// If Cbf != nullptr: write bf16 output (no bias). Else f32 (+bias).
// Tile 128x64, BK=32, 256 threads = 4 waves (2x2), mfma_f32_16x16x32_bf16.
// ---------------------------------------------------------------------------
__global__ __launch_bounds__(256) void gemm_mfma_split(
    const float* __restrict__ A, const float* __restrict__ Bt,
    const float* __restrict__ bias, float* __restrict__ C,
    unsigned short* __restrict__ Cbf,
    int M, int K, int N)
{
    __shared__ unsigned short AsH[128][32];
    __shared__ unsigned short AsL[128][32];
    __shared__ unsigned short BsH[64][32];
    __shared__ unsigned short BsL[64][32];

    const int tid = threadIdx.x;
    const int bm = blockIdx.x * 128;
    const int bn = blockIdx.y * 64;

    const int sr = tid >> 2;          // 0..63
    const int sk = (tid & 3) * 8;     // 0,8,16,24

    const int wid = tid >> 6;
    const int lane = tid & 63;
    const int wr = (wid >> 1) * 64;
    const int wc = (wid & 1) * 32;
    const int fr = lane & 15;
    const int fk = (lane >> 4) * 8;

    float4v acc[4][2];
    #pragma unroll
    for (int m = 0; m < 4; ++m)
        #pragma unroll
        for (int n = 0; n < 2; ++n)
            acc[m][n] = (float4v){0.f, 0.f, 0.f, 0.f};

    for (int k0 = 0; k0 < K; k0 += 32) {
        #pragma unroll
        for (int rr = 0; rr < 2; ++rr) {
            int r = sr + rr * 64;
            int gr = bm + r;
            float4 v0 = make_float4(0.f, 0.f, 0.f, 0.f);
            float4 v1 = make_float4(0.f, 0.f, 0.f, 0.f);
            if (gr < M) {
                const float* p = &A[(size_t)gr * K + k0 + sk];
                v0 = *reinterpret_cast<const float4*>(p);
                v1 = *reinterpret_cast<const float4*>(p + 4);
            }
            float vv[8] = {v0.x, v0.y, v0.z, v0.w, v1.x, v1.y, v1.z, v1.w};
            short8v h8, l8;
            #pragma unroll
            for (int j = 0; j < 8; ++j) {
                unsigned short hb = f2bf(vv[j]);
                h8[j] = (short)hb;
                l8[j] = (short)f2bf(vv[j] - bf2f(hb));
            }
            *reinterpret_cast<short8v*>(&AsH[r][sk]) = h8;
            *reinterpret_cast<short8v*>(&AsL[r][sk]) = l8;
        }
        {
            const float* p = &Bt[(size_t)(bn + sr) * K + k0 + sk];
            float4 v0 = *reinterpret_cast<const float4*>(p);
            float4 v1 = *reinterpret_cast<const float4*>(p + 4);
            float vv[8] = {v0.x, v0.y, v0.z, v0.w, v1.x, v1.y, v1.z, v1.w};
            short8v h8, l8;
            #pragma unroll
            for (int j = 0; j < 8; ++j) {
                unsigned short hb = f2bf(vv[j]);
                h8[j] = (short)hb;
                l8[j] = (short)f2bf(vv[j] - bf2f(hb));
            }
            *reinterpret_cast<short8v*>(&BsH[sr][sk]) = h8;
            *reinterpret_cast<short8v*>(&BsL[sr][sk]) = l8;
        }
        __syncthreads();

        short8v aH[4], aL[4], bH[2], bL[2];
        #pragma unroll
        for (int m = 0; m < 4; ++m) {
            aH[m] = *reinterpret_cast<const short8v*>(&AsH[wr + m * 16 + fr][fk]);
            aL[m] = *reinterpret_cast<const short8v*>(&AsL[wr + m * 16 + fr][fk]);
        }
        #pragma unroll
        for (int n = 0; n < 2; ++n) {
            bH[n] = *reinterpret_cast<const short8v*>(&BsH[wc + n * 16 + fr][fk]);
            bL[n] = *reinterpret_cast<const short8v*>(&BsL[wc + n * 16 + fr][fk]);
        }
        #pragma unroll
        for (int m = 0; m < 4; ++m) {
            #pragma unroll
            for (int n = 0; n < 2; ++n) {
                acc[m][n] = __builtin_amdgcn_mfma_f32_16x16x32_bf16(aH[m], bH[n], acc[m][n], 0, 0, 0);
                acc[m][n] = __builtin_amdgcn_mfma_f32_16x16x32_bf16(aH[m], bL[n], acc[m][n], 0, 0, 0);
                acc[m][n] = __builtin_amdgcn_mfma_f32_16x16x32_bf16(aL[m], bH[n], acc[m][n], 0, 0, 0);
            }
        }
        __syncthreads();
    }

    // epilogue: C/D layout col=lane&15, row=(lane>>4)*4+r
    #pragma unroll
    for (int m = 0; m < 4; ++m) {
        int row = bm + wr + m * 16 + (lane >> 4) * 4;
        #pragma unroll
        for (int n = 0; n < 2; ++n) {
            int col = bn + wc + n * 16 + fr;
            float b = bias ? bias[col] : 0.f;
            #pragma unroll
            for (int r = 0; r < 4; ++r) {
                if (row + r < M) {
                    if (Cbf) Cbf[(size_t)(row + r) * N + col] = f2bf(acc[m][n][r]);
                    else     C[(size_t)(row + r) * N + col] = acc[m][n][r] + b;
                }
            }
        }
    }
}

// ---------------------------------------------------------------------------
// f1[n,h] = sum_d Wh[n,h*64+d]*a_s[h,d] (Wh bf16)
// ---------------------------------------------------------------------------
__global__ __launch_bounds__(64) void node_scores(
    const unsigned short* __restrict__ Wh, const float* __restrict__ a_s,
    const float* __restrict__ a_d, float* __restrict__ f1,
    float* __restrict__ f2, int n_nodes)
{
    int n = blockIdx.x;
    if (n >= n_nodes) return;
    int lane = threadIdx.x;
    #pragma unroll
    for (int h = 0; h < HEADS; ++h) {
        float w = bf2f(Wh[(size_t)n * HD + h * DH + lane]);
        float v1 = w * a_s[h * DH + lane];
        float v2 = w * a_d[h * DH + lane];
        #pragma unroll
        for (int m = 32; m; m >>= 1) {
            v1 += __shfl_xor(v1, m);
            v2 += __shfl_xor(v2, m);
        }
        if (lane == 0) {
            f1[(size_t)n * HEADS + h] = v1;
            f2[(size_t)n * HEADS + h] = v2;
        }
    }
}

// ---------------------------------------------------------------------------
// Fused per-node: LeakyReLU scores -> segment softmax -> SpMM (bf16 Wh) -> ELU
// ---------------------------------------------------------------------------
__global__ __launch_bounds__(256) void gat_node(
    const unsigned short* __restrict__ Wh, const float* __restrict__ f1,
    const float* __restrict__ f2, const int* __restrict__ row_ptr,
    const int* __restrict__ dst, float* __restrict__ out, int n_nodes)
{
    __shared__ float s_f1[HEADS];
    __shared__ float s_m[HEADS];
    __shared__ float s_inv[HEADS];
    __shared__ float red[256];
    __shared__ int   s_dst[64];
    __shared__ float s_p[64][HEADS];

    const int n = blockIdx.x;
    if (n >= n_nodes) return;
    const int tid = threadIdx.x;
    const int lo = row_ptr[n], hi = row_ptr[n + 1];
    const int deg = hi - lo;

    const int h_out = tid >> 5;       // 0..7
    const int dp = (tid & 31) * 2;    // even d within head
    float acc0 = 0.f, acc1 = 0.f;

    if (deg > 0) {
        if (tid < HEADS) s_f1[tid] = f1[(size_t)n * HEADS + tid];
        __syncthreads();
        const int myh = tid & 7;
        const float f1h = s_f1[myh];

        float lmax = -INFINITY;
        for (int idx = tid; idx < deg * HEADS; idx += 256) {
            int j = idx >> 3;
            int dn = dst[lo + j];
            float e = f1h + f2[(size_t)dn * HEADS + myh];
            e = e > 0.f ? e : ALPHA * e;
            lmax = fmaxf(lmax, e);
        }
        red[tid] = lmax;
        __syncthreads();
        for (int s = 128; s >= 8; s >>= 1) {
            if (tid < s) red[tid] = fmaxf(red[tid], red[tid + s]);
            __syncthreads();
        }
        if (tid < HEADS) s_m[tid] = red[tid];
        __syncthreads();
        const float mh = s_m[myh];

        float lsum = 0.f;
        for (int idx = tid; idx < deg * HEADS; idx += 256) {
            int j = idx >> 3;
            int dn = dst[lo + j];
            float e = f1h + f2[(size_t)dn * HEADS + myh];
            e = e > 0.f ? e : ALPHA * e;
            lsum += __expf(e - mh);
        }
        red[tid] = lsum;
        __syncthreads();
        for (int s = 128; s >= 8; s >>= 1) {
            if (tid < s) red[tid] += red[tid + s];
            __syncthreads();
        }
        if (tid < HEADS) s_inv[tid] = 1.f / fmaxf(red[tid], 1e-16f);
        __syncthreads();

        for (int c0 = 0; c0 < deg; c0 += 64) {
            int cn = min(64, deg - c0);
            if (tid < cn) s_dst[tid] = dst[lo + c0 + tid];
            __syncthreads();
            for (int idx = tid; idx < cn * HEADS; idx += 256) {
                int j = idx >> 3;
                int hh = idx & 7;
                int dn = s_dst[j];
                float e = s_f1[hh] + f2[(size_t)dn * HEADS + hh];
                e = e > 0.f ? e : ALPHA * e;
                s_p[j][hh] = __expf(e - s_m[hh]) * s_inv[hh];
            }
            __syncthreads();
            for (int j = 0; j < cn; ++j) {
                float p = s_p[j][h_out];
                unsigned int u = *reinterpret_cast<const unsigned int*>(
                    &Wh[(size_t)s_dst[j] * HD + h_out * DH + dp]);
                acc0 += p * bf2f((unsigned short)(u & 0xffffu));
                acc1 += p * bf2f((unsigned short)(u >> 16));
            }
            __syncthreads();
        }
    }

    float o0 = acc0 > 0.f ? acc0 : expm1f(acc0);
    float o1 = acc1 > 0.f ? acc1 : expm1f(acc1);
    float2 o = make_float2(o0, o1);
    *reinterpret_cast<float2*>(&out[(size_t)n * HD + h_out * DH + dp]) = o;
}

// ---------------------------------------------------------------------------
extern "C" void kernel_launch(void* const* d_in, const int* in_sizes, int n_in,
                              void* d_out, int out_size, void* d_ws, size_t ws_size,
                              hipStream_t stream) {
    const float* x      = (const float*)d_in[0];
    const int*   e_src  = (const int*)d_in[1];
    const int*   e_dst  = (const int*)d_in[2];
    const float* W1     = (const float*)d_in[3];
    const float* a_src1 = (const float*)d_in[4];
    const float* a_dst1 = (const float*)d_in[5];
    const float* W2     = (const float*)d_in[6];
    const float* a_src2 = (const float*)d_in[7];
    const float* a_dst2 = (const float*)d_in[8];
    const float* lin_W  = (const float*)d_in[9];
    const float* lin_b  = (const float*)d_in[10];
    float* outp = (float*)d_out;

    // workspace: WhBf (bf16) | h (f32) | f1 | f2 | rowptr | BtW1 | BtW2 | BtLin
    unsigned short* WhBf = (unsigned short*)d_ws;
    float* bufH  = (float*)(WhBf + (size_t)N_NODES * HD);
    float* f1    = bufH + (size_t)N_NODES * HD;
    float* f2    = f1 + (size_t)N_NODES * HEADS;
    int* rowptr  = (int*)(f2 + (size_t)N_NODES * HEADS);
    float* BtW1  = (float*)(rowptr + N_NODES + 64);
    float* BtW2  = BtW1 + (size_t)HD * 256;
    float* BtLin = BtW2 + (size_t)HD * HD;

    build_rowptr<<<(N_NODES + 256) / 256, 256, 0, stream>>>(e_src, N_EDGES, N_NODES, rowptr);
    transpose_w<<<(HEADS * 256 * DH + 255) / 256, 256, 0, stream>>>(W1, BtW1, 256, HEADS * 256 * DH);
    transpose_w<<<(HEADS * HD * DH + 255) / 256, 256, 0, stream>>>(W2, BtW2, HD, HEADS * HD * DH);
    transpose_w<<<(HD * 64 + 255) / 256, 256, 0, stream>>>(lin_W, BtLin, HD, HD * 64);

    dim3 g1((N_NODES + 127) / 128, HD / 64);
    // layer 1: WhBf = bf16(x @ W1)
    gemm_mfma_split<<<g1, 256, 0, stream>>>(x, BtW1, nullptr, nullptr, WhBf, N_NODES, 256, HD);
    node_scores<<<N_NODES, 64, 0, stream>>>(WhBf, a_src1, a_dst1, f1, f2, N_NODES);
    gat_node<<<N_NODES, 256, 0, stream>>>(WhBf, f1, f2, rowptr, e_dst, bufH, N_NODES);

    // layer 2
    gemm_mfma_split<<<g1, 256, 0, stream>>>(bufH, BtW2, nullptr, nullptr, WhBf, N_NODES, HD, HD);
    node_scores<<<N_NODES, 64, 0, stream>>>(WhBf, a_src2, a_dst2, f1, f2, N_NODES);
    gat_node<<<N_NODES, 256, 0, stream>>>(WhBf, f1, f2, rowptr, e_dst, bufH, N_NODES);

    // output: f32 + bias
    dim3 g3((N_NODES + 127) / 128, 1);
    gemm_mfma_split<<<g3, 256, 0, stream>>>(bufH, BtLin, lin_b, outp, nullptr, N_NODES, HD, 64);
}

// Round 4
// 543.726 us; speedup vs baseline: 2.2094x; 1.2675x over previous
//
#include <hip/hip_runtime.h>
#include <hip/hip_bf16.h>
#include <math.h>

#define ALPHA 0.2f
#define N_NODES 50000
#define N_EDGES 800000
#define HEADS 8
#define DH 64
#define HD 512   // HEADS*DH
#define DCAP 128 // edges per softmax/gather chunk (per wave)

typedef __attribute__((ext_vector_type(8))) short short8v;
typedef __attribute__((ext_vector_type(4))) float float4v;

// round-to-nearest-even f32 -> bf16 bits
__device__ __forceinline__ unsigned short f2bf(float f) {
    unsigned int u = __float_as_uint(f);
    unsigned int r = (u + 0x7fffu + ((u >> 16) & 1u)) >> 16;
    return (unsigned short)r;
}
__device__ __forceinline__ float bf2f(unsigned short h) {
    return __uint_as_float(((unsigned int)h) << 16);
}

// ---------------------------------------------------------------------------
// row_ptr[n] = lower_bound(edge_src, n)  (edge_src is sorted ascending)
// ---------------------------------------------------------------------------
__global__ void build_rowptr(const int* __restrict__ src, int E, int n_nodes,
                             int* __restrict__ row_ptr) {
    int n = blockIdx.x * blockDim.x + threadIdx.x;
    if (n > n_nodes) return;
    int lo = 0, hi = E;
    while (lo < hi) {
        int mid = (lo + hi) >> 1;
        if (src[mid] < n) lo = mid + 1; else hi = mid;
    }
    row_ptr[n] = lo;
}

// ---------------------------------------------------------------------------
// W[h][f][d]  ->  Bt[(h*64+d)][F]   (f32, tiny)
// ---------------------------------------------------------------------------
__global__ void transpose_w(const float* __restrict__ in, float* __restrict__ out,
                            int F, int total) {
    int idx = blockIdx.x * 256 + threadIdx.x;
    if (idx >= total) return;
    int d = idx & 63;
    int f = (idx >> 6) % F;
    int h = idx / (F << 6);
    out[(size_t)((h << 6) + d) * F + f] = in[idx];
}

// ---------------------------------------------------------------------------
// Split-bf16 MFMA GEMM, fp32 A in, fp32-accurate.
// If Cbf != nullptr: write bf16 output (no bias). Else f32 (+bias).
// Tile 128x64, BK=32, 256 threads = 4 waves (2x2), mfma_f32_16x16x32_bf16.
// ---------------------------------------------------------------------------
__global__ __launch_bounds__(256) void gemm_mfma_split(
    const float* __restrict__ A, const float* __restrict__ Bt,
    const float* __restrict__ bias, float* __restrict__ C,
    unsigned short* __restrict__ Cbf,
    int M, int K, int N)
{
    __shared__ unsigned short AsH[128][32];
    __shared__ unsigned short AsL[128][32];
    __shared__ unsigned short BsH[64][32];
    __shared__ unsigned short BsL[64][32];

    const int tid = threadIdx.x;
    const int bm = blockIdx.x * 128;
    const int bn = blockIdx.y * 64;

    const int sr = tid >> 2;          // 0..63
    const int sk = (tid & 3) * 8;     // 0,8,16,24

    const int wid = tid >> 6;
    const int lane = tid & 63;
    const int wr = (wid >> 1) * 64;
    const int wc = (wid & 1) * 32;
    const int fr = lane & 15;
    const int fk = (lane >> 4) * 8;

    float4v acc[4][2];
    #pragma unroll
    for (int m = 0; m < 4; ++m)
        #pragma unroll
        for (int n = 0; n < 2; ++n)
            acc[m][n] = (float4v){0.f, 0.f, 0.f, 0.f};

    for (int k0 = 0; k0 < K; k0 += 32) {
        #pragma unroll
        for (int rr = 0; rr < 2; ++rr) {
            int r = sr + rr * 64;
            int gr = bm + r;
            float4 v0 = make_float4(0.f, 0.f, 0.f, 0.f);
            float4 v1 = make_float4(0.f, 0.f, 0.f, 0.f);
            if (gr < M) {
                const float* p = &A[(size_t)gr * K + k0 + sk];
                v0 = *reinterpret_cast<const float4*>(p);
                v1 = *reinterpret_cast<const float4*>(p + 4);
            }
            float vv[8] = {v0.x, v0.y, v0.z, v0.w, v1.x, v1.y, v1.z, v1.w};
            short8v h8, l8;
            #pragma unroll
            for (int j = 0; j < 8; ++j) {
                unsigned short hb = f2bf(vv[j]);
                h8[j] = (short)hb;
                l8[j] = (short)f2bf(vv[j] - bf2f(hb));
            }
            *reinterpret_cast<short8v*>(&AsH[r][sk]) = h8;
            *reinterpret_cast<short8v*>(&AsL[r][sk]) = l8;
        }
        {
            const float* p = &Bt[(size_t)(bn + sr) * K + k0 + sk];
            float4 v0 = *reinterpret_cast<const float4*>(p);
            float4 v1 = *reinterpret_cast<const float4*>(p + 4);
            float vv[8] = {v0.x, v0.y, v0.z, v0.w, v1.x, v1.y, v1.z, v1.w};
            short8v h8, l8;
            #pragma unroll
            for (int j = 0; j < 8; ++j) {
                unsigned short hb = f2bf(vv[j]);
                h8[j] = (short)hb;
                l8[j] = (short)f2bf(vv[j] - bf2f(hb));
            }
            *reinterpret_cast<short8v*>(&BsH[sr][sk]) = h8;
            *reinterpret_cast<short8v*>(&BsL[sr][sk]) = l8;
        }
        __syncthreads();

        short8v aH[4], aL[4], bH[2], bL[2];
        #pragma unroll
        for (int m = 0; m < 4; ++m) {
            aH[m] = *reinterpret_cast<const short8v*>(&AsH[wr + m * 16 + fr][fk]);
            aL[m] = *reinterpret_cast<const short8v*>(&AsL[wr + m * 16 + fr][fk]);
        }
        #pragma unroll
        for (int n = 0; n < 2; ++n) {
            bH[n] = *reinterpret_cast<const short8v*>(&BsH[wc + n * 16 + fr][fk]);
            bL[n] = *reinterpret_cast<const short8v*>(&BsL[wc + n * 16 + fr][fk]);
        }
        #pragma unroll
        for (int m = 0; m < 4; ++m) {
            #pragma unroll
            for (int n = 0; n < 2; ++n) {
                acc[m][n] = __builtin_amdgcn_mfma_f32_16x16x32_bf16(aH[m], bH[n], acc[m][n], 0, 0, 0);
                acc[m][n] = __builtin_amdgcn_mfma_f32_16x16x32_bf16(aH[m], bL[n], acc[m][n], 0, 0, 0);
                acc[m][n] = __builtin_amdgcn_mfma_f32_16x16x32_bf16(aL[m], bH[n], acc[m][n], 0, 0, 0);
            }
        }
        __syncthreads();
    }

    #pragma unroll
    for (int m = 0; m < 4; ++m) {
        int row = bm + wr + m * 16 + (lane >> 4) * 4;
        #pragma unroll
        for (int n = 0; n < 2; ++n) {
            int col = bn + wc + n * 16 + fr;
            float b = bias ? bias[col] : 0.f;
            #pragma unroll
            for (int r = 0; r < 4; ++r) {
                if (row + r < M) {
                    if (Cbf) Cbf[(size_t)(row + r) * N + col] = f2bf(acc[m][n][r]);
                    else     C[(size_t)(row + r) * N + col] = acc[m][n][r] + b;
                }
            }
        }
    }
}

// ---------------------------------------------------------------------------
// node_scores, wave-per-node: lane = (head hl=lane>>3, dimgroup (lane&7)*8).
// Each lane: 16B bf16 load (8 dims), dot with a_s/a_d, reduce over 8 lanes.
// ---------------------------------------------------------------------------
__global__ __launch_bounds__(256) void node_scores_wave(
    const unsigned short* __restrict__ Wh, const float* __restrict__ a_s,
    const float* __restrict__ a_d, float* __restrict__ f1,
    float* __restrict__ f2, int n_nodes)
{
    const int wv = threadIdx.x >> 6;
    const int lane = threadIdx.x & 63;
    const int n = blockIdx.x * 4 + wv;
    if (n >= n_nodes) return;

    const int hl = lane >> 3;
    const int dg = (lane & 7) * 8;

    uint4 u = *reinterpret_cast<const uint4*>(&Wh[(size_t)n * HD + hl * DH + dg]);
    float4 s0 = *reinterpret_cast<const float4*>(&a_s[hl * DH + dg]);
    float4 s1 = *reinterpret_cast<const float4*>(&a_s[hl * DH + dg + 4]);
    float4 d0 = *reinterpret_cast<const float4*>(&a_d[hl * DH + dg]);
    float4 d1 = *reinterpret_cast<const float4*>(&a_d[hl * DH + dg + 4]);

    unsigned int uu[4] = {u.x, u.y, u.z, u.w};
    float w[8];
    #pragma unroll
    for (int q = 0; q < 4; ++q) {
        w[2 * q]     = __uint_as_float(uu[q] << 16);
        w[2 * q + 1] = __uint_as_float(uu[q] & 0xffff0000u);
    }
    float sv[8] = {s0.x, s0.y, s0.z, s0.w, s1.x, s1.y, s1.z, s1.w};
    float dv[8] = {d0.x, d0.y, d0.z, d0.w, d1.x, d1.y, d1.z, d1.w};

    float v1 = 0.f, v2 = 0.f;
    #pragma unroll
    for (int q = 0; q < 8; ++q) {
        v1 += w[q] * sv[q];
        v2 += w[q] * dv[q];
    }
    #pragma unroll
    for (int m = 1; m <= 4; m <<= 1) {
        v1 += __shfl_xor(v1, m);
        v2 += __shfl_xor(v2, m);
    }
    if ((lane & 7) == 0) {
        f1[(size_t)n * HEADS + hl] = v1;
        f2[(size_t)n * HEADS + hl] = v2;
    }
}

// ---------------------------------------------------------------------------
// gat_node, wave-per-node, no block barriers.
// Softmax phase: lane=(j8=lane>>3, h=lane&7): 8 edges x 8 heads per step,
//   shfl_xor(8,16,32) reduces over edge slots.
// Gather phase: lane=(hl=lane>>3, dg=(lane&7)*8): 16B/lane per edge.
// Unnormalized p in wave-private LDS; normalize once at the end.
// ---------------------------------------------------------------------------
__global__ __launch_bounds__(256) void gat_node_wave(
    const unsigned short* __restrict__ Wh, const float* __restrict__ f1,
    const float* __restrict__ f2, const int* __restrict__ row_ptr,
    const int* __restrict__ dst, float* __restrict__ out, int n_nodes)
{
    __shared__ float s_p[4][DCAP][HEADS];   // 16 KB
    __shared__ int   s_dst[4][DCAP];        // 2 KB

    const int wv = threadIdx.x >> 6;
    const int lane = threadIdx.x & 63;
    const int n = blockIdx.x * 4 + wv;
    if (n >= n_nodes) return;

    const int lo = row_ptr[n], hi = row_ptr[n + 1];
    const int deg = hi - lo;

    const int h  = lane & 7;     // softmax-phase head
    const int j8 = lane >> 3;    // softmax-phase edge slot
    const int hl = lane >> 3;    // gather-phase head
    const int dg = (lane & 7) * 8;

    const float f1h = f1[(size_t)n * HEADS + h];

    // ---- pass 1: per-head max ----
    float m = -INFINITY;
    for (int b0 = 0; b0 < deg; b0 += 8) {
        int j = b0 + j8;
        float e = -INFINITY;
        if (j < deg) {
            int dn = dst[lo + j];
            e = f1h + f2[(size_t)dn * HEADS + h];
            e = e > 0.f ? e : ALPHA * e;
        }
        m = fmaxf(m, e);
    }
    #pragma unroll
    for (int mk = 8; mk <= 32; mk <<= 1) m = fmaxf(m, __shfl_xor(m, mk));

    // ---- pass 2 per chunk: p -> LDS (+running sum), then gather ----
    float ssum = 0.f;
    float acc[8] = {0.f, 0.f, 0.f, 0.f, 0.f, 0.f, 0.f, 0.f};

    for (int c0 = 0; c0 < deg; c0 += DCAP) {
        int cn = min(DCAP, deg - c0);
        for (int b0 = 0; b0 < cn; b0 += 8) {
            int j = b0 + j8;
            float p = 0.f;
            if (j < cn) {
                int dn = dst[lo + c0 + j];
                float e = f1h + f2[(size_t)dn * HEADS + h];
                e = e > 0.f ? e : ALPHA * e;
                p = __expf(e - m);
                s_p[wv][j][h] = p;
                if (h == 0) s_dst[wv][j] = dn;
            }
            ssum += p;
        }
        // wave-local LDS write->read fence (no cross-wave coupling)
        asm volatile("s_waitcnt lgkmcnt(0)" ::: "memory");

        #pragma unroll 2
        for (int j = 0; j < cn; ++j) {
            int dn = s_dst[wv][j];
            float p = s_p[wv][j][hl];
            uint4 u = *reinterpret_cast<const uint4*>(
                &Wh[(size_t)dn * HD + hl * DH + dg]);
            unsigned int uu[4] = {u.x, u.y, u.z, u.w};
            #pragma unroll
            for (int q = 0; q < 4; ++q) {
                acc[2 * q]     += p * __uint_as_float(uu[q] << 16);
                acc[2 * q + 1] += p * __uint_as_float(uu[q] & 0xffff0000u);
            }
        }
        // reads of s_p/s_dst complete before next chunk overwrites
        asm volatile("s_waitcnt lgkmcnt(0)" ::: "memory");
    }

    // ---- normalize + ELU + store ----
    #pragma unroll
    for (int mk = 8; mk <= 32; mk <<= 1) ssum += __shfl_xor(ssum, mk);
    float inv = 1.f / fmaxf(ssum, 1e-16f);   // valid for head h = lane&7
    float invg = __shfl(inv, hl);            // fetch inv for head hl (any lane with lane&7==hl)

    float o[8];
    #pragma unroll
    for (int q = 0; q < 8; ++q) {
        float v = acc[q] * invg;
        o[q] = v > 0.f ? v : expm1f(v);
    }
    float* op = &out[(size_t)n * HD + hl * DH + dg];
    *reinterpret_cast<float4*>(op)     = make_float4(o[0], o[1], o[2], o[3]);
    *reinterpret_cast<float4*>(op + 4) = make_float4(o[4], o[5], o[6], o[7]);
}

// ---------------------------------------------------------------------------
extern "C" void kernel_launch(void* const* d_in, const int* in_sizes, int n_in,
                              void* d_out, int out_size, void* d_ws, size_t ws_size,
                              hipStream_t stream) {
    const float* x      = (const float*)d_in[0];
    const int*   e_src  = (const int*)d_in[1];
    const int*   e_dst  = (const int*)d_in[2];
    const float* W1     = (const float*)d_in[3];
    const float* a_src1 = (const float*)d_in[4];
    const float* a_dst1 = (const float*)d_in[5];
    const float* W2     = (const float*)d_in[6];
    const float* a_src2 = (const float*)d_in[7];
    const float* a_dst2 = (const float*)d_in[8];
    const float* lin_W  = (const float*)d_in[9];
    const float* lin_b  = (const float*)d_in[10];
    float* outp = (float*)d_out;

    unsigned short* WhBf = (unsigned short*)d_ws;
    float* bufH  = (float*)(WhBf + (size_t)N_NODES * HD);
    float* f1    = bufH + (size_t)N_NODES * HD;
    float* f2    = f1 + (size_t)N_NODES * HEADS;
    int* rowptr  = (int*)(f2 + (size_t)N_NODES * HEADS);
    float* BtW1  = (float*)(rowptr + N_NODES + 64);
    float* BtW2  = BtW1 + (size_t)HD * 256;
    float* BtLin = BtW2 + (size_t)HD * HD;

    build_rowptr<<<(N_NODES + 256) / 256, 256, 0, stream>>>(e_src, N_EDGES, N_NODES, rowptr);
    transpose_w<<<(HEADS * 256 * DH + 255) / 256, 256, 0, stream>>>(W1, BtW1, 256, HEADS * 256 * DH);
    transpose_w<<<(HEADS * HD * DH + 255) / 256, 256, 0, stream>>>(W2, BtW2, HD, HEADS * HD * DH);
    transpose_w<<<(HD * 64 + 255) / 256, 256, 0, stream>>>(lin_W, BtLin, HD, HD * 64);

    const int nwb = (N_NODES + 3) / 4;   // 4 nodes (waves) per block
    dim3 g1((N_NODES + 127) / 128, HD / 64);

    // layer 1
    gemm_mfma_split<<<g1, 256, 0, stream>>>(x, BtW1, nullptr, nullptr, WhBf, N_NODES, 256, HD);
    node_scores_wave<<<nwb, 256, 0, stream>>>(WhBf, a_src1, a_dst1, f1, f2, N_NODES);
    gat_node_wave<<<nwb, 256, 0, stream>>>(WhBf, f1, f2, rowptr, e_dst, bufH, N_NODES);

    // layer 2
    gemm_mfma_split<<<g1, 256, 0, stream>>>(bufH, BtW2, nullptr, nullptr, WhBf, N_NODES, HD, HD);
    node_scores_wave<<<nwb, 256, 0, stream>>>(WhBf, a_src2, a_dst2, f1, f2, N_NODES);
    gat_node_wave<<<nwb, 256, 0, stream>>>(WhBf, f1, f2, rowptr, e_dst, bufH, N_NODES);

    // output
    dim3 g3((N_NODES + 127) / 128, 1);
    gemm_mfma_split<<<g3, 256, 0, stream>>>(bufH, BtLin, lin_b, outp, nullptr, N_NODES, HD, 64);
}

// Round 5
// 472.562 us; speedup vs baseline: 2.5422x; 1.1506x over previous
//
#include <hip/hip_runtime.h>
#include <hip/hip_bf16.h>
#include <math.h>

#define ALPHA 0.2f
#define N_NODES 50000
#define N_EDGES 800000
#define HEADS 8
#define DH 64
#define HD 512   // HEADS*DH
#define DCAP 128 // edges per softmax/gather chunk (per wave)

typedef __attribute__((ext_vector_type(8))) short short8v;
typedef __attribute__((ext_vector_type(4))) float float4v;

// round-to-nearest-even f32 -> bf16 bits
__device__ __forceinline__ unsigned short f2bf(float f) {
    unsigned int u = __float_as_uint(f);
    unsigned int r = (u + 0x7fffu + ((u >> 16) & 1u)) >> 16;
    return (unsigned short)r;
}
__device__ __forceinline__ float bf2f(unsigned short h) {
    return __uint_as_float(((unsigned int)h) << 16);
}

// async global->LDS, 16B per lane; lds dest = wave-uniform base + lane*16
__device__ __forceinline__ void gl_lds16(const unsigned short* g, unsigned short* l) {
    __builtin_amdgcn_global_load_lds(
        (const __attribute__((address_space(1))) unsigned int*)(g),
        (__attribute__((address_space(3))) unsigned int*)(l),
        16, 0, 0);
}

// ---------------------------------------------------------------------------
__global__ void build_rowptr(const int* __restrict__ src, int E, int n_nodes,
                             int* __restrict__ row_ptr) {
    int n = blockIdx.x * blockDim.x + threadIdx.x;
    if (n > n_nodes) return;
    int lo = 0, hi = E;
    while (lo < hi) {
        int mid = (lo + hi) >> 1;
        if (src[mid] < n) lo = mid + 1; else hi = mid;
    }
    row_ptr[n] = lo;
}

// ---------------------------------------------------------------------------
// x f32 -> bf16, 8 elems/thread
// ---------------------------------------------------------------------------
__global__ __launch_bounds__(256) void cast_bf16(
    const float* __restrict__ in, unsigned short* __restrict__ out, int total8) {
    int i = blockIdx.x * 256 + threadIdx.x;
    if (i >= total8) return;
    const float4* p = reinterpret_cast<const float4*>(in + (size_t)i * 8);
    float4 v0 = p[0], v1 = p[1];
    float vv[8] = {v0.x, v0.y, v0.z, v0.w, v1.x, v1.y, v1.z, v1.w};
    short8v o;
    #pragma unroll
    for (int q = 0; q < 8; ++q) o[q] = (short)f2bf(vv[q]);
    *reinterpret_cast<short8v*>(out + (size_t)i * 8) = o;
}

// ---------------------------------------------------------------------------
// W[h][f][d] f32  ->  BtH/BtL[(h*64+d)][F] bf16 hi/lo
// ---------------------------------------------------------------------------
__global__ void transpose_w_split(const float* __restrict__ in,
                                  unsigned short* __restrict__ outH,
                                  unsigned short* __restrict__ outL,
                                  int F, int total) {
    int idx = blockIdx.x * 256 + threadIdx.x;
    if (idx >= total) return;
    int d = idx & 63;
    int f = (idx >> 6) % F;
    int h = idx / (F << 6);
    float v = in[idx];
    unsigned short hb = f2bf(v);
    size_t o = (size_t)((h << 6) + d) * F + f;
    outH[o] = hb;
    outL[o] = f2bf(v - bf2f(hb));
}

// ---------------------------------------------------------------------------
// C[M,N] = A(bf16)[M,K] @ (BH+BL)(bf16)[N,K]^T (+bias)
// Tile 128x128, BK=64, 256 threads = 4 waves (2x2, each 64x64).
// A/B staged via global_load_lds w/ XOR-swizzled source; swizzled ds_read.
// ---------------------------------------------------------------------------
__global__ __launch_bounds__(256) void gemm_bf16A(
    const unsigned short* __restrict__ A,
    const unsigned short* __restrict__ BH,
    const unsigned short* __restrict__ BL,
    const float* __restrict__ bias,
    float* __restrict__ C, unsigned short* __restrict__ Cbf,
    int M, int K, int N)
{
    __shared__ unsigned short As[128][64];
    __shared__ unsigned short BsH[128][64];
    __shared__ unsigned short BsL[128][64];

    const int tid = threadIdx.x;
    const int bm = blockIdx.x * 128;
    const int bn = blockIdx.y * 128;
    const int wid = tid >> 6;
    const int lane = tid & 63;

    const int wr = (wid >> 1) * 64;
    const int wc = (wid & 1) * 64;
    const int fr = lane & 15;
    const int fks = (lane >> 4) * 8;

    // staging: each wave-issue covers 8 rows x 64 cols (1 KB);
    // lane's global col pre-swizzled so linear LDS + swizzled read match
    const int a_r = lane >> 3;
    const int a_c = 8 * ((lane & 7) ^ a_r);

    float4v acc[4][4];
    #pragma unroll
    for (int m = 0; m < 4; ++m)
        #pragma unroll
        for (int n = 0; n < 4; ++n)
            acc[m][n] = (float4v){0.f, 0.f, 0.f, 0.f};

    for (int k0 = 0; k0 < K; k0 += 64) {
        #pragma unroll
        for (int i = 0; i < 4; ++i) {
            int g = wid * 4 + i;
            int row = bm + g * 8 + a_r; if (row >= M) row = M - 1;
            gl_lds16(&A[(size_t)row * K + k0 + a_c], &As[g * 8][0]);
        }
        #pragma unroll
        for (int i = 0; i < 4; ++i) {
            int g = wid * 4 + i;
            int row = bn + g * 8 + a_r; if (row >= N) row = N - 1;
            const size_t off = (size_t)row * K + k0 + a_c;
            gl_lds16(&BH[off], &BsH[g * 8][0]);
            gl_lds16(&BL[off], &BsL[g * 8][0]);
        }
        __syncthreads();

        #pragma unroll
        for (int ks = 0; ks < 2; ++ks) {
            const int fko = ks * 32 + fks;
            short8v aF[4], bHf[4], bLf[4];
            #pragma unroll
            for (int m = 0; m < 4; ++m) {
                int rr = wr + m * 16 + fr;
                aF[m] = *reinterpret_cast<const short8v*>(&As[rr][fko ^ ((rr & 7) * 8)]);
            }
            #pragma unroll
            for (int n = 0; n < 4; ++n) {
                int cc = wc + n * 16 + fr;
                int col = fko ^ ((cc & 7) * 8);
                bHf[n] = *reinterpret_cast<const short8v*>(&BsH[cc][col]);
                bLf[n] = *reinterpret_cast<const short8v*>(&BsL[cc][col]);
            }
            #pragma unroll
            for (int m = 0; m < 4; ++m)
                #pragma unroll
                for (int n = 0; n < 4; ++n) {
                    acc[m][n] = __builtin_amdgcn_mfma_f32_16x16x32_bf16(aF[m], bHf[n], acc[m][n], 0, 0, 0);
                    acc[m][n] = __builtin_amdgcn_mfma_f32_16x16x32_bf16(aF[m], bLf[n], acc[m][n], 0, 0, 0);
                }
        }
        __syncthreads();
    }

    // epilogue: C/D layout col=lane&15, row=(lane>>4)*4+r
    #pragma unroll
    for (int m = 0; m < 4; ++m) {
        int row0 = bm + wr + m * 16 + (lane >> 4) * 4;
        #pragma unroll
        for (int n = 0; n < 4; ++n) {
            int col = bn + wc + n * 16 + fr;
            if (col >= N) continue;
            float b = bias ? bias[col] : 0.f;
            #pragma unroll
            for (int r = 0; r < 4; ++r) {
                int row = row0 + r;
                if (row < M) {
                    if (Cbf) Cbf[(size_t)row * N + col] = f2bf(acc[m][n][r]);
                    else     C[(size_t)row * N + col] = acc[m][n][r] + b;
                }
            }
        }
    }
}

// ---------------------------------------------------------------------------
// node_scores, wave-per-node
// ---------------------------------------------------------------------------
__global__ __launch_bounds__(256) void node_scores_wave(
    const unsigned short* __restrict__ Wh, const float* __restrict__ a_s,
    const float* __restrict__ a_d, float* __restrict__ f1,
    float* __restrict__ f2, int n_nodes)
{
    const int wv = threadIdx.x >> 6;
    const int lane = threadIdx.x & 63;
    const int n = blockIdx.x * 4 + wv;
    if (n >= n_nodes) return;

    const int hl = lane >> 3;
    const int dg = (lane & 7) * 8;

    uint4 u = *reinterpret_cast<const uint4*>(&Wh[(size_t)n * HD + hl * DH + dg]);
    float4 s0 = *reinterpret_cast<const float4*>(&a_s[hl * DH + dg]);
    float4 s1 = *reinterpret_cast<const float4*>(&a_s[hl * DH + dg + 4]);
    float4 d0 = *reinterpret_cast<const float4*>(&a_d[hl * DH + dg]);
    float4 d1 = *reinterpret_cast<const float4*>(&a_d[hl * DH + dg + 4]);

    unsigned int uu[4] = {u.x, u.y, u.z, u.w};
    float w[8];
    #pragma unroll
    for (int q = 0; q < 4; ++q) {
        w[2 * q]     = __uint_as_float(uu[q] << 16);
        w[2 * q + 1] = __uint_as_float(uu[q] & 0xffff0000u);
    }
    float sv[8] = {s0.x, s0.y, s0.z, s0.w, s1.x, s1.y, s1.z, s1.w};
    float dv[8] = {d0.x, d0.y, d0.z, d0.w, d1.x, d1.y, d1.z, d1.w};

    float v1 = 0.f, v2 = 0.f;
    #pragma unroll
    for (int q = 0; q < 8; ++q) {
        v1 += w[q] * sv[q];
        v2 += w[q] * dv[q];
    }
    #pragma unroll
    for (int m = 1; m <= 4; m <<= 1) {
        v1 += __shfl_xor(v1, m);
        v2 += __shfl_xor(v2, m);
    }
    if ((lane & 7) == 0) {
        f1[(size_t)n * HEADS + hl] = v1;
        f2[(size_t)n * HEADS + hl] = v2;
    }
}

// ---------------------------------------------------------------------------
// gat_node, wave-per-node, no block barriers; bf16 output.
// ---------------------------------------------------------------------------
__global__ __launch_bounds__(256) void gat_node_wave(
    const unsigned short* __restrict__ Wh, const float* __restrict__ f1,
    const float* __restrict__ f2, const int* __restrict__ row_ptr,
    const int* __restrict__ dst, unsigned short* __restrict__ out, int n_nodes)
{
    __shared__ float s_p[4][DCAP][HEADS];   // 16 KB
    __shared__ int   s_dst[4][DCAP];        // 2 KB

    const int wv = threadIdx.x >> 6;
    const int lane = threadIdx.x & 63;
    const int n = blockIdx.x * 4 + wv;
    if (n >= n_nodes) return;

    const int lo = row_ptr[n], hi = row_ptr[n + 1];
    const int deg = hi - lo;

    const int h  = lane & 7;
    const int j8 = lane >> 3;
    const int hl = lane >> 3;
    const int dg = (lane & 7) * 8;

    const float f1h = f1[(size_t)n * HEADS + h];

    float m = -INFINITY;
    for (int b0 = 0; b0 < deg; b0 += 8) {
        int j = b0 + j8;
        float e = -INFINITY;
        if (j < deg) {
            int dn = dst[lo + j];
            e = f1h + f2[(size_t)dn * HEADS + h];
            e = e > 0.f ? e : ALPHA * e;
        }
        m = fmaxf(m, e);
    }
    #pragma unroll
    for (int mk = 8; mk <= 32; mk <<= 1) m = fmaxf(m, __shfl_xor(m, mk));

    float ssum = 0.f;
    float acc[8] = {0.f, 0.f, 0.f, 0.f, 0.f, 0.f, 0.f, 0.f};

    for (int c0 = 0; c0 < deg; c0 += DCAP) {
        int cn = min(DCAP, deg - c0);
        for (int b0 = 0; b0 < cn; b0 += 8) {
            int j = b0 + j8;
            float p = 0.f;
            if (j < cn) {
                int dn = dst[lo + c0 + j];
                float e = f1h + f2[(size_t)dn * HEADS + h];
                e = e > 0.f ? e : ALPHA * e;
                p = __expf(e - m);
                s_p[wv][j][h] = p;
                if (h == 0) s_dst[wv][j] = dn;
            }
            ssum += p;
        }
        asm volatile("s_waitcnt lgkmcnt(0)" ::: "memory");

        #pragma unroll 2
        for (int j = 0; j < cn; ++j) {
            int dn = s_dst[wv][j];
            float p = s_p[wv][j][hl];
            uint4 u = *reinterpret_cast<const uint4*>(
                &Wh[(size_t)dn * HD + hl * DH + dg]);
            unsigned int uu[4] = {u.x, u.y, u.z, u.w};
            #pragma unroll
            for (int q = 0; q < 4; ++q) {
                acc[2 * q]     += p * __uint_as_float(uu[q] << 16);
                acc[2 * q + 1] += p * __uint_as_float(uu[q] & 0xffff0000u);
            }
        }
        asm volatile("s_waitcnt lgkmcnt(0)" ::: "memory");
    }

    #pragma unroll
    for (int mk = 8; mk <= 32; mk <<= 1) ssum += __shfl_xor(ssum, mk);
    float inv = 1.f / fmaxf(ssum, 1e-16f);
    float invg = __shfl(inv, hl);

    short8v o8;
    #pragma unroll
    for (int q = 0; q < 8; ++q) {
        float v = acc[q] * invg;
        v = v > 0.f ? v : expm1f(v);
        o8[q] = (short)f2bf(v);
    }
    *reinterpret_cast<short8v*>(&out[(size_t)n * HD + hl * DH + dg]) = o8;
}

// ---------------------------------------------------------------------------
extern "C" void kernel_launch(void* const* d_in, const int* in_sizes, int n_in,
                              void* d_out, int out_size, void* d_ws, size_t ws_size,
                              hipStream_t stream) {
    const float* x      = (const float*)d_in[0];
    const int*   e_src  = (const int*)d_in[1];
    const int*   e_dst  = (const int*)d_in[2];
    const float* W1     = (const float*)d_in[3];
    const float* a_src1 = (const float*)d_in[4];
    const float* a_dst1 = (const float*)d_in[5];
    const float* W2     = (const float*)d_in[6];
    const float* a_src2 = (const float*)d_in[7];
    const float* a_dst2 = (const float*)d_in[8];
    const float* lin_W  = (const float*)d_in[9];
    const float* lin_b  = (const float*)d_in[10];
    float* outp = (float*)d_out;

    const size_t NHD = (size_t)N_NODES * HD;       // 25.6M
    unsigned short* WhBf = (unsigned short*)d_ws;  // 51.2 MB
    unsigned short* hBf  = WhBf + NHD;             // 51.2 MB
    unsigned short* xBf  = hBf + NHD;              // 25.6 MB
    float* f1    = (float*)(xBf + (size_t)N_NODES * 256);
    float* f2    = f1 + (size_t)N_NODES * HEADS;
    int* rowptr  = (int*)(f2 + (size_t)N_NODES * HEADS);
    unsigned short* BtW1H = (unsigned short*)(rowptr + N_NODES + 64);
    unsigned short* BtW1L = BtW1H + (size_t)HD * 256;
    unsigned short* BtW2H = BtW1L + (size_t)HD * 256;
    unsigned short* BtW2L = BtW2H + (size_t)HD * HD;
    unsigned short* BtLinH = BtW2L + (size_t)HD * HD;
    unsigned short* BtLinL = BtLinH + (size_t)64 * HD;

    build_rowptr<<<(N_NODES + 256) / 256, 256, 0, stream>>>(e_src, N_EDGES, N_NODES, rowptr);
    cast_bf16<<<(N_NODES * 256 / 8 + 255) / 256, 256, 0, stream>>>(x, xBf, N_NODES * 256 / 8);
    transpose_w_split<<<(HEADS * 256 * DH + 255) / 256, 256, 0, stream>>>(W1, BtW1H, BtW1L, 256, HEADS * 256 * DH);
    transpose_w_split<<<(HEADS * HD * DH + 255) / 256, 256, 0, stream>>>(W2, BtW2H, BtW2L, HD, HEADS * HD * DH);
    transpose_w_split<<<(HD * 64 + 255) / 256, 256, 0, stream>>>(lin_W, BtLinH, BtLinL, HD, HD * 64);

    const int nwb = (N_NODES + 3) / 4;
    dim3 g1((N_NODES + 127) / 128, HD / 128);

    // layer 1
    gemm_bf16A<<<g1, 256, 0, stream>>>(xBf, BtW1H, BtW1L, nullptr, nullptr, WhBf, N_NODES, 256, HD);
    node_scores_wave<<<nwb, 256, 0, stream>>>(WhBf, a_src1, a_dst1, f1, f2, N_NODES);
    gat_node_wave<<<nwb, 256, 0, stream>>>(WhBf, f1, f2, rowptr, e_dst, hBf, N_NODES);

    // layer 2
    gemm_bf16A<<<g1, 256, 0, stream>>>(hBf, BtW2H, BtW2L, nullptr, nullptr, WhBf, N_NODES, HD, HD);
    node_scores_wave<<<nwb, 256, 0, stream>>>(WhBf, a_src2, a_dst2, f1, f2, N_NODES);
    gat_node_wave<<<nwb, 256, 0, stream>>>(WhBf, f1, f2, rowptr, e_dst, hBf, N_NODES);

    // output: f32 + bias
    dim3 g3((N_NODES + 127) / 128, 1);
    gemm_bf16A<<<g3, 256, 0, stream>>>(hBf, BtLinH, BtLinL, lin_b, outp, nullptr, N_NODES, HD, 64);
}

// Round 6
// 468.627 us; speedup vs baseline: 2.5635x; 1.0084x over previous
//
#include <hip/hip_runtime.h>
#include <hip/hip_bf16.h>
#include <math.h>

#define ALPHA 0.2f
#define N_NODES 50000
#define N_EDGES 800000
#define HEADS 8
#define DH 64
#define HD 512   // HEADS*DH
#define DCAP 128 // edges per softmax/gather chunk (per wave)

typedef __attribute__((ext_vector_type(8))) short short8v;
typedef __attribute__((ext_vector_type(4))) float float4v;

// round-to-nearest-even f32 -> bf16 bits
__device__ __forceinline__ unsigned short f2bf(float f) {
    unsigned int u = __float_as_uint(f);
    unsigned int r = (u + 0x7fffu + ((u >> 16) & 1u)) >> 16;
    return (unsigned short)r;
}
__device__ __forceinline__ float bf2f(unsigned short h) {
    return __uint_as_float(((unsigned int)h) << 16);
}

// async global->LDS, 16B per lane; lds dest = wave-uniform base + lane*16
__device__ __forceinline__ void gl_lds16(const unsigned short* g, unsigned short* l) {
    __builtin_amdgcn_global_load_lds(
        (const __attribute__((address_space(1))) unsigned int*)(g),
        (__attribute__((address_space(3))) unsigned int*)(l),
        16, 0, 0);
}

// ---------------------------------------------------------------------------
__global__ void build_rowptr(const int* __restrict__ src, int E, int n_nodes,
                             int* __restrict__ row_ptr) {
    int n = blockIdx.x * blockDim.x + threadIdx.x;
    if (n > n_nodes) return;
    int lo = 0, hi = E;
    while (lo < hi) {
        int mid = (lo + hi) >> 1;
        if (src[mid] < n) lo = mid + 1; else hi = mid;
    }
    row_ptr[n] = lo;
}

// ---------------------------------------------------------------------------
__global__ __launch_bounds__(256) void cast_bf16(
    const float* __restrict__ in, unsigned short* __restrict__ out, int total8) {
    int i = blockIdx.x * 256 + threadIdx.x;
    if (i >= total8) return;
    const float4* p = reinterpret_cast<const float4*>(in + (size_t)i * 8);
    float4 v0 = p[0], v1 = p[1];
    float vv[8] = {v0.x, v0.y, v0.z, v0.w, v1.x, v1.y, v1.z, v1.w};
    short8v o;
    #pragma unroll
    for (int q = 0; q < 8; ++q) o[q] = (short)f2bf(vv[q]);
    *reinterpret_cast<short8v*>(out + (size_t)i * 8) = o;
}

// ---------------------------------------------------------------------------
// W[h][f][d] f32  ->  BtH/BtL[(h*64+d)][F] bf16 hi/lo
// ---------------------------------------------------------------------------
__global__ void transpose_w_split(const float* __restrict__ in,
                                  unsigned short* __restrict__ outH,
                                  unsigned short* __restrict__ outL,
                                  int F, int total) {
    int idx = blockIdx.x * 256 + threadIdx.x;
    if (idx >= total) return;
    int d = idx & 63;
    int f = (idx >> 6) % F;
    int h = idx / (F << 6);
    float v = in[idx];
    unsigned short hb = f2bf(v);
    size_t o = (size_t)((h << 6) + d) * F + f;
    outH[o] = hb;
    outL[o] = f2bf(v - bf2f(hb));
}

// ---------------------------------------------------------------------------
// C[M,N] = A(bf16)[M,K] @ (BH+BL)(bf16)[N,K]^T (+bias)
// Tile 128x128, BK=64, 256 threads = 4 waves (2x2, each 64x64).
// ---------------------------------------------------------------------------
__global__ __launch_bounds__(256) void gemm_bf16A(
    const unsigned short* __restrict__ A,
    const unsigned short* __restrict__ BH,
    const unsigned short* __restrict__ BL,
    const float* __restrict__ bias,
    float* __restrict__ C, unsigned short* __restrict__ Cbf,
    int M, int K, int N)
{
    __shared__ unsigned short As[128][64];
    __shared__ unsigned short BsH[128][64];
    __shared__ unsigned short BsL[128][64];

    const int tid = threadIdx.x;
    const int bm = blockIdx.x * 128;
    const int bn = blockIdx.y * 128;
    const int wid = tid >> 6;
    const int lane = tid & 63;

    const int wr = (wid >> 1) * 64;
    const int wc = (wid & 1) * 64;
    const int fr = lane & 15;
    const int fks = (lane >> 4) * 8;

    const int a_r = lane >> 3;
    const int a_c = 8 * ((lane & 7) ^ a_r);

    float4v acc[4][4];
    #pragma unroll
    for (int m = 0; m < 4; ++m)
        #pragma unroll
        for (int n = 0; n < 4; ++n)
            acc[m][n] = (float4v){0.f, 0.f, 0.f, 0.f};

    for (int k0 = 0; k0 < K; k0 += 64) {
        #pragma unroll
        for (int i = 0; i < 4; ++i) {
            int g = wid * 4 + i;
            int row = bm + g * 8 + a_r; if (row >= M) row = M - 1;
            gl_lds16(&A[(size_t)row * K + k0 + a_c], &As[g * 8][0]);
        }
        #pragma unroll
        for (int i = 0; i < 4; ++i) {
            int g = wid * 4 + i;
            int row = bn + g * 8 + a_r; if (row >= N) row = N - 1;
            const size_t off = (size_t)row * K + k0 + a_c;
            gl_lds16(&BH[off], &BsH[g * 8][0]);
            gl_lds16(&BL[off], &BsL[g * 8][0]);
        }
        __syncthreads();

        #pragma unroll
        for (int ks = 0; ks < 2; ++ks) {
            const int fko = ks * 32 + fks;
            short8v aF[4], bHf[4], bLf[4];
            #pragma unroll
            for (int m = 0; m < 4; ++m) {
                int rr = wr + m * 16 + fr;
                aF[m] = *reinterpret_cast<const short8v*>(&As[rr][fko ^ ((rr & 7) * 8)]);
            }
            #pragma unroll
            for (int n = 0; n < 4; ++n) {
                int cc = wc + n * 16 + fr;
                int col = fko ^ ((cc & 7) * 8);
                bHf[n] = *reinterpret_cast<const short8v*>(&BsH[cc][col]);
                bLf[n] = *reinterpret_cast<const short8v*>(&BsL[cc][col]);
            }
            #pragma unroll
            for (int m = 0; m < 4; ++m)
                #pragma unroll
                for (int n = 0; n < 4; ++n) {
                    acc[m][n] = __builtin_amdgcn_mfma_f32_16x16x32_bf16(aF[m], bHf[n], acc[m][n], 0, 0, 0);
                    acc[m][n] = __builtin_amdgcn_mfma_f32_16x16x32_bf16(aF[m], bLf[n], acc[m][n], 0, 0, 0);
                }
        }
        __syncthreads();
    }

    #pragma unroll
    for (int m = 0; m < 4; ++m) {
        int row0 = bm + wr + m * 16 + (lane >> 4) * 4;
        #pragma unroll
        for (int n = 0; n < 4; ++n) {
            int col = bn + wc + n * 16 + fr;
            if (col >= N) continue;
            float b = bias ? bias[col] : 0.f;
            #pragma unroll
            for (int r = 0; r < 4; ++r) {
                int row = row0 + r;
                if (row < M) {
                    if (Cbf) Cbf[(size_t)row * N + col] = f2bf(acc[m][n][r]);
                    else     C[(size_t)row * N + col] = acc[m][n][r] + b;
                }
            }
        }
    }
}

// ---------------------------------------------------------------------------
// node_scores, wave-per-node
// ---------------------------------------------------------------------------
__global__ __launch_bounds__(256) void node_scores_wave(
    const unsigned short* __restrict__ Wh, const float* __restrict__ a_s,
    const float* __restrict__ a_d, float* __restrict__ f1,
    float* __restrict__ f2, int n_nodes)
{
    const int wv = threadIdx.x >> 6;
    const int lane = threadIdx.x & 63;
    const int n = blockIdx.x * 4 + wv;
    if (n >= n_nodes) return;

    const int hl = lane >> 3;
    const int dg = (lane & 7) * 8;

    uint4 u = *reinterpret_cast<const uint4*>(&Wh[(size_t)n * HD + hl * DH + dg]);
    float4 s0 = *reinterpret_cast<const float4*>(&a_s[hl * DH + dg]);
    float4 s1 = *reinterpret_cast<const float4*>(&a_s[hl * DH + dg + 4]);
    float4 d0 = *reinterpret_cast<const float4*>(&a_d[hl * DH + dg]);
    float4 d1 = *reinterpret_cast<const float4*>(&a_d[hl * DH + dg + 4]);

    unsigned int uu[4] = {u.x, u.y, u.z, u.w};
    float w[8];
    #pragma unroll
    for (int q = 0; q < 4; ++q) {
        w[2 * q]     = __uint_as_float(uu[q] << 16);
        w[2 * q + 1] = __uint_as_float(uu[q] & 0xffff0000u);
    }
    float sv[8] = {s0.x, s0.y, s0.z, s0.w, s1.x, s1.y, s1.z, s1.w};
    float dv[8] = {d0.x, d0.y, d0.z, d0.w, d1.x, d1.y, d1.z, d1.w};

    float v1 = 0.f, v2 = 0.f;
    #pragma unroll
    for (int q = 0; q < 8; ++q) {
        v1 += w[q] * sv[q];
        v2 += w[q] * dv[q];
    }
    #pragma unroll
    for (int m = 1; m <= 4; m <<= 1) {
        v1 += __shfl_xor(v1, m);
        v2 += __shfl_xor(v2, m);
    }
    if ((lane & 7) == 0) {
        f1[(size_t)n * HEADS + hl] = v1;
        f2[(size_t)n * HEADS + hl] = v2;
    }
}

// ---------------------------------------------------------------------------
// gat_node, wave-per-node, no block barriers; bf16 output.
// Gather phase: 4-deep software pipeline (4 outstanding dwordx4/lane).
// ---------------------------------------------------------------------------
__global__ __launch_bounds__(256) void gat_node_wave(
    const unsigned short* __restrict__ Wh, const float* __restrict__ f1,
    const float* __restrict__ f2, const int* __restrict__ row_ptr,
    const int* __restrict__ dst, unsigned short* __restrict__ out, int n_nodes)
{
    __shared__ float s_p[4][DCAP][HEADS];   // 16 KB
    __shared__ int   s_dst[4][DCAP];        // 2 KB

    const int wv = threadIdx.x >> 6;
    const int lane = threadIdx.x & 63;
    const int n = blockIdx.x * 4 + wv;
    if (n >= n_nodes) return;

    const int lo = row_ptr[n], hi = row_ptr[n + 1];
    const int deg = hi - lo;

    const int h  = lane & 7;
    const int j8 = lane >> 3;
    const int hl = lane >> 3;
    const int dg = (lane & 7) * 8;
    const size_t base = (size_t)hl * DH + dg;

    const float f1h = f1[(size_t)n * HEADS + h];

    float m = -INFINITY;
    for (int b0 = 0; b0 < deg; b0 += 8) {
        int j = b0 + j8;
        float e = -INFINITY;
        if (j < deg) {
            int dn = dst[lo + j];
            e = f1h + f2[(size_t)dn * HEADS + h];
            e = e > 0.f ? e : ALPHA * e;
        }
        m = fmaxf(m, e);
    }
    #pragma unroll
    for (int mk = 8; mk <= 32; mk <<= 1) m = fmaxf(m, __shfl_xor(m, mk));

    float ssum = 0.f;
    float acc[8] = {0.f, 0.f, 0.f, 0.f, 0.f, 0.f, 0.f, 0.f};

    for (int c0 = 0; c0 < deg; c0 += DCAP) {
        int cn = min(DCAP, deg - c0);
        for (int b0 = 0; b0 < cn; b0 += 8) {
            int j = b0 + j8;
            float p = 0.f;
            if (j < cn) {
                int dn = dst[lo + c0 + j];
                float e = f1h + f2[(size_t)dn * HEADS + h];
                e = e > 0.f ? e : ALPHA * e;
                p = __expf(e - m);
                s_p[wv][j][h] = p;
                if (h == 0) s_dst[wv][j] = dn;
            }
            ssum += p;
        }
        asm volatile("s_waitcnt lgkmcnt(0)" ::: "memory");

        // ---- gather: 4-deep pipeline ----
        int j = 0;
        for (; j + 4 <= cn; j += 4) {
            int dn0 = s_dst[wv][j + 0];
            int dn1 = s_dst[wv][j + 1];
            int dn2 = s_dst[wv][j + 2];
            int dn3 = s_dst[wv][j + 3];
            float p0 = s_p[wv][j + 0][hl];
            float p1 = s_p[wv][j + 1][hl];
            float p2 = s_p[wv][j + 2][hl];
            float p3 = s_p[wv][j + 3][hl];
            uint4 u0 = *reinterpret_cast<const uint4*>(&Wh[(size_t)dn0 * HD + base]);
            uint4 u1 = *reinterpret_cast<const uint4*>(&Wh[(size_t)dn1 * HD + base]);
            uint4 u2 = *reinterpret_cast<const uint4*>(&Wh[(size_t)dn2 * HD + base]);
            uint4 u3 = *reinterpret_cast<const uint4*>(&Wh[(size_t)dn3 * HD + base]);
            unsigned int w0[4] = {u0.x, u0.y, u0.z, u0.w};
            unsigned int w1[4] = {u1.x, u1.y, u1.z, u1.w};
            unsigned int w2[4] = {u2.x, u2.y, u2.z, u2.w};
            unsigned int w3[4] = {u3.x, u3.y, u3.z, u3.w};
            #pragma unroll
            for (int q = 0; q < 4; ++q) {
                acc[2 * q]     += p0 * __uint_as_float(w0[q] << 16);
                acc[2 * q + 1] += p0 * __uint_as_float(w0[q] & 0xffff0000u);
                acc[2 * q]     += p1 * __uint_as_float(w1[q] << 16);
                acc[2 * q + 1] += p1 * __uint_as_float(w1[q] & 0xffff0000u);
                acc[2 * q]     += p2 * __uint_as_float(w2[q] << 16);
                acc[2 * q + 1] += p2 * __uint_as_float(w2[q] & 0xffff0000u);
                acc[2 * q]     += p3 * __uint_as_float(w3[q] << 16);
                acc[2 * q + 1] += p3 * __uint_as_float(w3[q] & 0xffff0000u);
            }
        }
        for (; j < cn; ++j) {
            int dn = s_dst[wv][j];
            float p = s_p[wv][j][hl];
            uint4 u = *reinterpret_cast<const uint4*>(&Wh[(size_t)dn * HD + base]);
            unsigned int uu[4] = {u.x, u.y, u.z, u.w};
            #pragma unroll
            for (int q = 0; q < 4; ++q) {
                acc[2 * q]     += p * __uint_as_float(uu[q] << 16);
                acc[2 * q + 1] += p * __uint_as_float(uu[q] & 0xffff0000u);
            }
        }
        asm volatile("s_waitcnt lgkmcnt(0)" ::: "memory");
    }

    #pragma unroll
    for (int mk = 8; mk <= 32; mk <<= 1) ssum += __shfl_xor(ssum, mk);
    float inv = 1.f / fmaxf(ssum, 1e-16f);
    float invg = __shfl(inv, hl);

    short8v o8;
    #pragma unroll
    for (int q = 0; q < 8; ++q) {
        float v = acc[q] * invg;
        v = v > 0.f ? v : expm1f(v);
        o8[q] = (short)f2bf(v);
    }
    *reinterpret_cast<short8v*>(&out[(size_t)n * HD + hl * DH + dg]) = o8;
}

// ---------------------------------------------------------------------------
extern "C" void kernel_launch(void* const* d_in, const int* in_sizes, int n_in,
                              void* d_out, int out_size, void* d_ws, size_t ws_size,
                              hipStream_t stream) {
    const float* x      = (const float*)d_in[0];
    const int*   e_src  = (const int*)d_in[1];
    const int*   e_dst  = (const int*)d_in[2];
    const float* W1     = (const float*)d_in[3];
    const float* a_src1 = (const float*)d_in[4];
    const float* a_dst1 = (const float*)d_in[5];
    const float* W2     = (const float*)d_in[6];
    const float* a_src2 = (const float*)d_in[7];
    const float* a_dst2 = (const float*)d_in[8];
    const float* lin_W  = (const float*)d_in[9];
    const float* lin_b  = (const float*)d_in[10];
    float* outp = (float*)d_out;

    const size_t NHD = (size_t)N_NODES * HD;       // 25.6M
    unsigned short* WhBf = (unsigned short*)d_ws;  // 51.2 MB
    unsigned short* hBf  = WhBf + NHD;             // 51.2 MB
    unsigned short* xBf  = hBf + NHD;              // 25.6 MB
    float* f1    = (float*)(xBf + (size_t)N_NODES * 256);
    float* f2    = f1 + (size_t)N_NODES * HEADS;
    int* rowptr  = (int*)(f2 + (size_t)N_NODES * HEADS);
    unsigned short* BtW1H = (unsigned short*)(rowptr + N_NODES + 64);
    unsigned short* BtW1L = BtW1H + (size_t)HD * 256;
    unsigned short* BtW2H = BtW1L + (size_t)HD * 256;
    unsigned short* BtW2L = BtW2H + (size_t)HD * HD;
    unsigned short* BtLinH = BtW2L + (size_t)HD * HD;
    unsigned short* BtLinL = BtLinH + (size_t)64 * HD;

    build_rowptr<<<(N_NODES + 256) / 256, 256, 0, stream>>>(e_src, N_EDGES, N_NODES, rowptr);
    cast_bf16<<<(N_NODES * 256 / 8 + 255) / 256, 256, 0, stream>>>(x, xBf, N_NODES * 256 / 8);
    transpose_w_split<<<(HEADS * 256 * DH + 255) / 256, 256, 0, stream>>>(W1, BtW1H, BtW1L, 256, HEADS * 256 * DH);
    transpose_w_split<<<(HEADS * HD * DH + 255) / 256, 256, 0, stream>>>(W2, BtW2H, BtW2L, HD, HEADS * HD * DH);
    transpose_w_split<<<(HD * 64 + 255) / 256, 256, 0, stream>>>(lin_W, BtLinH, BtLinL, HD, HD * 64);

    const int nwb = (N_NODES + 3) / 4;
    dim3 g1((N_NODES + 127) / 128, HD / 128);

    // layer 1
    gemm_bf16A<<<g1, 256, 0, stream>>>(xBf, BtW1H, BtW1L, nullptr, nullptr, WhBf, N_NODES, 256, HD);
    node_scores_wave<<<nwb, 256, 0, stream>>>(WhBf, a_src1, a_dst1, f1, f2, N_NODES);
    gat_node_wave<<<nwb, 256, 0, stream>>>(WhBf, f1, f2, rowptr, e_dst, hBf, N_NODES);

    // layer 2
    gemm_bf16A<<<g1, 256, 0, stream>>>(hBf, BtW2H, BtW2L, nullptr, nullptr, WhBf, N_NODES, HD, HD);
    node_scores_wave<<<nwb, 256, 0, stream>>>(WhBf, a_src2, a_dst2, f1, f2, N_NODES);
    gat_node_wave<<<nwb, 256, 0, stream>>>(WhBf, f1, f2, rowptr, e_dst, hBf, N_NODES);

    // output: f32 + bias
    dim3 g3((N_NODES + 127) / 128, 1);
    gemm_bf16A<<<g3, 256, 0, stream>>>(hBf, BtLinH, BtLinL, lin_b, outp, nullptr, N_NODES, HD, 64);
}

// Round 7
// 443.014 us; speedup vs baseline: 2.7117x; 1.0578x over previous
//
#include <hip/hip_runtime.h>
#include <hip/hip_bf16.h>
#include <math.h>

#define ALPHA 0.2f
#define N_NODES 50000
#define N_EDGES 800000
#define HEADS 8
#define DH 64
#define HD 512   // HEADS*DH
#define DCAP 128 // edges per softmax/gather chunk (per wave)

typedef __attribute__((ext_vector_type(8))) short short8v;
typedef __attribute__((ext_vector_type(4))) float float4v;

// round-to-nearest-even f32 -> bf16 bits
__device__ __forceinline__ unsigned short f2bf(float f) {
    unsigned int u = __float_as_uint(f);
    unsigned int r = (u + 0x7fffu + ((u >> 16) & 1u)) >> 16;
    return (unsigned short)r;
}
__device__ __forceinline__ float bf2f(unsigned short h) {
    return __uint_as_float(((unsigned int)h) << 16);
}

// async global->LDS, 16B per lane; lds dest = wave-uniform base + lane*16
__device__ __forceinline__ void gl_lds16(const unsigned short* g, unsigned short* l) {
    __builtin_amdgcn_global_load_lds(
        (const __attribute__((address_space(1))) unsigned int*)(g),
        (__attribute__((address_space(3))) unsigned int*)(l),
        16, 0, 0);
}

// ---------------------------------------------------------------------------
__global__ void build_rowptr(const int* __restrict__ src, int E, int n_nodes,
                             int* __restrict__ row_ptr) {
    int n = blockIdx.x * blockDim.x + threadIdx.x;
    if (n > n_nodes) return;
    int lo = 0, hi = E;
    while (lo < hi) {
        int mid = (lo + hi) >> 1;
        if (src[mid] < n) lo = mid + 1; else hi = mid;
    }
    row_ptr[n] = lo;
}

// ---------------------------------------------------------------------------
__global__ __launch_bounds__(256) void cast_bf16(
    const float* __restrict__ in, unsigned short* __restrict__ out, int total8) {
    int i = blockIdx.x * 256 + threadIdx.x;
    if (i >= total8) return;
    const float4* p = reinterpret_cast<const float4*>(in + (size_t)i * 8);
    float4 v0 = p[0], v1 = p[1];
    float vv[8] = {v0.x, v0.y, v0.z, v0.w, v1.x, v1.y, v1.z, v1.w};
    short8v o;
    #pragma unroll
    for (int q = 0; q < 8; ++q) o[q] = (short)f2bf(vv[q]);
    *reinterpret_cast<short8v*>(out + (size_t)i * 8) = o;
}

// ---------------------------------------------------------------------------
// W[h][f][d] f32  ->  Bt[(h*64+d)][F] bf16
// ---------------------------------------------------------------------------
__global__ void transpose_w_bf(const float* __restrict__ in,
                               unsigned short* __restrict__ outB,
                               int F, int total) {
    int idx = blockIdx.x * 256 + threadIdx.x;
    if (idx >= total) return;
    int d = idx & 63;
    int f = (idx >> 6) % F;
    int h = idx / (F << 6);
    outB[(size_t)((h << 6) + d) * F + f] = f2bf(in[idx]);
}

// ---------------------------------------------------------------------------
// C[M,N] = A(bf16)[M,K] @ B(bf16)[N,K]^T (+bias)
// Tile 128x128, BK=64, 256 threads = 4 waves (2x2, each 64x64).
// A/B staged via global_load_lds w/ XOR-swizzled source; swizzled ds_read.
// ---------------------------------------------------------------------------
__global__ __launch_bounds__(256) void gemm_bf16(
    const unsigned short* __restrict__ A,
    const unsigned short* __restrict__ B,
    const float* __restrict__ bias,
    float* __restrict__ C, unsigned short* __restrict__ Cbf,
    int M, int K, int N)
{
    __shared__ unsigned short As[128][64];
    __shared__ unsigned short Bs[128][64];

    const int tid = threadIdx.x;
    const int bm = blockIdx.x * 128;
    const int bn = blockIdx.y * 128;
    const int wid = tid >> 6;
    const int lane = tid & 63;

    const int wr = (wid >> 1) * 64;
    const int wc = (wid & 1) * 64;
    const int fr = lane & 15;
    const int fks = (lane >> 4) * 8;

    const int a_r = lane >> 3;
    const int a_c = 8 * ((lane & 7) ^ a_r);

    float4v acc[4][4];
    #pragma unroll
    for (int m = 0; m < 4; ++m)
        #pragma unroll
        for (int n = 0; n < 4; ++n)
            acc[m][n] = (float4v){0.f, 0.f, 0.f, 0.f};

    for (int k0 = 0; k0 < K; k0 += 64) {
        #pragma unroll
        for (int i = 0; i < 4; ++i) {
            int g = wid * 4 + i;
            int row = bm + g * 8 + a_r; if (row >= M) row = M - 1;
            gl_lds16(&A[(size_t)row * K + k0 + a_c], &As[g * 8][0]);
        }
        #pragma unroll
        for (int i = 0; i < 4; ++i) {
            int g = wid * 4 + i;
            int row = bn + g * 8 + a_r; if (row >= N) row = N - 1;
            gl_lds16(&B[(size_t)row * K + k0 + a_c], &Bs[g * 8][0]);
        }
        __syncthreads();

        #pragma unroll
        for (int ks = 0; ks < 2; ++ks) {
            const int fko = ks * 32 + fks;
            short8v aF[4], bF[4];
            #pragma unroll
            for (int m = 0; m < 4; ++m) {
                int rr = wr + m * 16 + fr;
                aF[m] = *reinterpret_cast<const short8v*>(&As[rr][fko ^ ((rr & 7) * 8)]);
            }
            #pragma unroll
            for (int n = 0; n < 4; ++n) {
                int cc = wc + n * 16 + fr;
                bF[n] = *reinterpret_cast<const short8v*>(&Bs[cc][fko ^ ((cc & 7) * 8)]);
            }
            #pragma unroll
            for (int m = 0; m < 4; ++m)
                #pragma unroll
                for (int n = 0; n < 4; ++n)
                    acc[m][n] = __builtin_amdgcn_mfma_f32_16x16x32_bf16(aF[m], bF[n], acc[m][n], 0, 0, 0);
        }
        __syncthreads();
    }

    // epilogue: C/D layout col=lane&15, row=(lane>>4)*4+r
    #pragma unroll
    for (int m = 0; m < 4; ++m) {
        int row0 = bm + wr + m * 16 + (lane >> 4) * 4;
        #pragma unroll
        for (int n = 0; n < 4; ++n) {
            int col = bn + wc + n * 16 + fr;
            if (col >= N) continue;
            float b = bias ? bias[col] : 0.f;
            #pragma unroll
            for (int r = 0; r < 4; ++r) {
                int row = row0 + r;
                if (row < M) {
                    if (Cbf) Cbf[(size_t)row * N + col] = f2bf(acc[m][n][r]);
                    else     C[(size_t)row * N + col] = acc[m][n][r] + b;
                }
            }
        }
    }
}

// ---------------------------------------------------------------------------
// node_scores, wave-per-node
// ---------------------------------------------------------------------------
__global__ __launch_bounds__(256) void node_scores_wave(
    const unsigned short* __restrict__ Wh, const float* __restrict__ a_s,
    const float* __restrict__ a_d, float* __restrict__ f1,
    float* __restrict__ f2, int n_nodes)
{
    const int wv = threadIdx.x >> 6;
    const int lane = threadIdx.x & 63;
    const int n = blockIdx.x * 4 + wv;
    if (n >= n_nodes) return;

    const int hl = lane >> 3;
    const int dg = (lane & 7) * 8;

    uint4 u = *reinterpret_cast<const uint4*>(&Wh[(size_t)n * HD + hl * DH + dg]);
    float4 s0 = *reinterpret_cast<const float4*>(&a_s[hl * DH + dg]);
    float4 s1 = *reinterpret_cast<const float4*>(&a_s[hl * DH + dg + 4]);
    float4 d0 = *reinterpret_cast<const float4*>(&a_d[hl * DH + dg]);
    float4 d1 = *reinterpret_cast<const float4*>(&a_d[hl * DH + dg + 4]);

    unsigned int uu[4] = {u.x, u.y, u.z, u.w};
    float w[8];
    #pragma unroll
    for (int q = 0; q < 4; ++q) {
        w[2 * q]     = __uint_as_float(uu[q] << 16);
        w[2 * q + 1] = __uint_as_float(uu[q] & 0xffff0000u);
    }
    float sv[8] = {s0.x, s0.y, s0.z, s0.w, s1.x, s1.y, s1.z, s1.w};
    float dv[8] = {d0.x, d0.y, d0.z, d0.w, d1.x, d1.y, d1.z, d1.w};

    float v1 = 0.f, v2 = 0.f;
    #pragma unroll
    for (int q = 0; q < 8; ++q) {
        v1 += w[q] * sv[q];
        v2 += w[q] * dv[q];
    }
    #pragma unroll
    for (int m = 1; m <= 4; m <<= 1) {
        v1 += __shfl_xor(v1, m);
        v2 += __shfl_xor(v2, m);
    }
    if ((lane & 7) == 0) {
        f1[(size_t)n * HEADS + hl] = v1;
        f2[(size_t)n * HEADS + hl] = v2;
    }
}

// ---------------------------------------------------------------------------
// gat_node, wave-per-node, no block barriers; bf16 output.
// ---------------------------------------------------------------------------
__global__ __launch_bounds__(256) void gat_node_wave(
    const unsigned short* __restrict__ Wh, const float* __restrict__ f1,
    const float* __restrict__ f2, const int* __restrict__ row_ptr,
    const int* __restrict__ dst, unsigned short* __restrict__ out, int n_nodes)
{
    __shared__ float s_p[4][DCAP][HEADS];   // 16 KB
    __shared__ int   s_dst[4][DCAP];        // 2 KB

    const int wv = threadIdx.x >> 6;
    const int lane = threadIdx.x & 63;
    const int n = blockIdx.x * 4 + wv;
    if (n >= n_nodes) return;

    const int lo = row_ptr[n], hi = row_ptr[n + 1];
    const int deg = hi - lo;

    const int h  = lane & 7;
    const int j8 = lane >> 3;
    const int hl = lane >> 3;
    const int dg = (lane & 7) * 8;
    const size_t base = (size_t)hl * DH + dg;

    const float f1h = f1[(size_t)n * HEADS + h];

    float m = -INFINITY;
    for (int b0 = 0; b0 < deg; b0 += 8) {
        int j = b0 + j8;
        float e = -INFINITY;
        if (j < deg) {
            int dn = dst[lo + j];
            e = f1h + f2[(size_t)dn * HEADS + h];
            e = e > 0.f ? e : ALPHA * e;
        }
        m = fmaxf(m, e);
    }
    #pragma unroll
    for (int mk = 8; mk <= 32; mk <<= 1) m = fmaxf(m, __shfl_xor(m, mk));

    float ssum = 0.f;
    float acc[8] = {0.f, 0.f, 0.f, 0.f, 0.f, 0.f, 0.f, 0.f};

    for (int c0 = 0; c0 < deg; c0 += DCAP) {
        int cn = min(DCAP, deg - c0);
        for (int b0 = 0; b0 < cn; b0 += 8) {
            int j = b0 + j8;
            float p = 0.f;
            if (j < cn) {
                int dn = dst[lo + c0 + j];
                float e = f1h + f2[(size_t)dn * HEADS + h];
                e = e > 0.f ? e : ALPHA * e;
                p = __expf(e - m);
                s_p[wv][j][h] = p;
                if (h == 0) s_dst[wv][j] = dn;
            }
            ssum += p;
        }
        asm volatile("s_waitcnt lgkmcnt(0)" ::: "memory");

        // ---- gather: 4-deep pipeline ----
        int j = 0;
        for (; j + 4 <= cn; j += 4) {
            int dn0 = s_dst[wv][j + 0];
            int dn1 = s_dst[wv][j + 1];
            int dn2 = s_dst[wv][j + 2];
            int dn3 = s_dst[wv][j + 3];
            float p0 = s_p[wv][j + 0][hl];
            float p1 = s_p[wv][j + 1][hl];
            float p2 = s_p[wv][j + 2][hl];
            float p3 = s_p[wv][j + 3][hl];
            uint4 u0 = *reinterpret_cast<const uint4*>(&Wh[(size_t)dn0 * HD + base]);
            uint4 u1 = *reinterpret_cast<const uint4*>(&Wh[(size_t)dn1 * HD + base]);
            uint4 u2 = *reinterpret_cast<const uint4*>(&Wh[(size_t)dn2 * HD + base]);
            uint4 u3 = *reinterpret_cast<const uint4*>(&Wh[(size_t)dn3 * HD + base]);
            unsigned int w0[4] = {u0.x, u0.y, u0.z, u0.w};
            unsigned int w1[4] = {u1.x, u1.y, u1.z, u1.w};
            unsigned int w2[4] = {u2.x, u2.y, u2.z, u2.w};
            unsigned int w3[4] = {u3.x, u3.y, u3.z, u3.w};
            #pragma unroll
            for (int q = 0; q < 4; ++q) {
                acc[2 * q]     += p0 * __uint_as_float(w0[q] << 16);
                acc[2 * q + 1] += p0 * __uint_as_float(w0[q] & 0xffff0000u);
                acc[2 * q]     += p1 * __uint_as_float(w1[q] << 16);
                acc[2 * q + 1] += p1 * __uint_as_float(w1[q] & 0xffff0000u);
                acc[2 * q]     += p2 * __uint_as_float(w2[q] << 16);
                acc[2 * q + 1] += p2 * __uint_as_float(w2[q] & 0xffff0000u);
                acc[2 * q]     += p3 * __uint_as_float(w3[q] << 16);
                acc[2 * q + 1] += p3 * __uint_as_float(w3[q] & 0xffff0000u);
            }
        }
        for (; j < cn; ++j) {
            int dn = s_dst[wv][j];
            float p = s_p[wv][j][hl];
            uint4 u = *reinterpret_cast<const uint4*>(&Wh[(size_t)dn * HD + base]);
            unsigned int uu[4] = {u.x, u.y, u.z, u.w};
            #pragma unroll
            for (int q = 0; q < 4; ++q) {
                acc[2 * q]     += p * __uint_as_float(uu[q] << 16);
                acc[2 * q + 1] += p * __uint_as_float(uu[q] & 0xffff0000u);
            }
        }
        asm volatile("s_waitcnt lgkmcnt(0)" ::: "memory");
    }

    #pragma unroll
    for (int mk = 8; mk <= 32; mk <<= 1) ssum += __shfl_xor(ssum, mk);
    float inv = 1.f / fmaxf(ssum, 1e-16f);
    float invg = __shfl(inv, hl);

    short8v o8;
    #pragma unroll
    for (int q = 0; q < 8; ++q) {
        float v = acc[q] * invg;
        v = v > 0.f ? v : expm1f(v);
        o8[q] = (short)f2bf(v);
    }
    *reinterpret_cast<short8v*>(&out[(size_t)n * HD + hl * DH + dg]) = o8;
}

// ---------------------------------------------------------------------------
extern "C" void kernel_launch(void* const* d_in, const int* in_sizes, int n_in,
                              void* d_out, int out_size, void* d_ws, size_t ws_size,
                              hipStream_t stream) {
    const float* x      = (const float*)d_in[0];
    const int*   e_src  = (const int*)d_in[1];
    const int*   e_dst  = (const int*)d_in[2];
    const float* W1     = (const float*)d_in[3];
    const float* a_src1 = (const float*)d_in[4];
    const float* a_dst1 = (const float*)d_in[5];
    const float* W2     = (const float*)d_in[6];
    const float* a_src2 = (const float*)d_in[7];
    const float* a_dst2 = (const float*)d_in[8];
    const float* lin_W  = (const float*)d_in[9];
    const float* lin_b  = (const float*)d_in[10];
    float* outp = (float*)d_out;

    const size_t NHD = (size_t)N_NODES * HD;       // 25.6M
    unsigned short* WhBf = (unsigned short*)d_ws;  // 51.2 MB
    unsigned short* hBf  = WhBf + NHD;             // 51.2 MB
    unsigned short* xBf  = hBf + NHD;              // 25.6 MB
    float* f1    = (float*)(xBf + (size_t)N_NODES * 256);
    float* f2    = f1 + (size_t)N_NODES * HEADS;
    int* rowptr  = (int*)(f2 + (size_t)N_NODES * HEADS);
    unsigned short* BtW1  = (unsigned short*)(rowptr + N_NODES + 64);
    unsigned short* BtW2  = BtW1 + (size_t)HD * 256;
    unsigned short* BtLin = BtW2 + (size_t)HD * HD;

    build_rowptr<<<(N_NODES + 256) / 256, 256, 0, stream>>>(e_src, N_EDGES, N_NODES, rowptr);
    cast_bf16<<<(N_NODES * 256 / 8 + 255) / 256, 256, 0, stream>>>(x, xBf, N_NODES * 256 / 8);
    transpose_w_bf<<<(HEADS * 256 * DH + 255) / 256, 256, 0, stream>>>(W1, BtW1, 256, HEADS * 256 * DH);
    transpose_w_bf<<<(HEADS * HD * DH + 255) / 256, 256, 0, stream>>>(W2, BtW2, HD, HEADS * HD * DH);
    transpose_w_bf<<<(HD * 64 + 255) / 256, 256, 0, stream>>>(lin_W, BtLin, HD, HD * 64);

    const int nwb = (N_NODES + 3) / 4;
    dim3 g1((N_NODES + 127) / 128, HD / 128);

    // layer 1
    gemm_bf16<<<g1, 256, 0, stream>>>(xBf, BtW1, nullptr, nullptr, WhBf, N_NODES, 256, HD);
    node_scores_wave<<<nwb, 256, 0, stream>>>(WhBf, a_src1, a_dst1, f1, f2, N_NODES);
    gat_node_wave<<<nwb, 256, 0, stream>>>(WhBf, f1, f2, rowptr, e_dst, hBf, N_NODES);

    // layer 2
    gemm_bf16<<<g1, 256, 0, stream>>>(hBf, BtW2, nullptr, nullptr, WhBf, N_NODES, HD, HD);
    node_scores_wave<<<nwb, 256, 0, stream>>>(WhBf, a_src2, a_dst2, f1, f2, N_NODES);
    gat_node_wave<<<nwb, 256, 0, stream>>>(WhBf, f1, f2, rowptr, e_dst, hBf, N_NODES);

    // output: f32 + bias
    dim3 g3((N_NODES + 127) / 128, 1);
    gemm_bf16<<<g3, 256, 0, stream>>>(hBf, BtLin, lin_b, outp, nullptr, N_NODES, HD, 64);
}

// Round 8
// 397.751 us; speedup vs baseline: 3.0203x; 1.1138x over previous
//
#include <hip/hip_runtime.h>
#include <hip/hip_bf16.h>
#include <math.h>

#define ALPHA 0.2f
#define N_NODES 50000
#define N_EDGES 800000
#define HEADS 8
#define DH 64
#define HD 512   // HEADS*DH
#define DCAP 128 // edges per softmax/gather chunk (per wave)

typedef __attribute__((ext_vector_type(8))) short short8v;
typedef __attribute__((ext_vector_type(4))) float float4v;

// round-to-nearest-even f32 -> bf16 bits
__device__ __forceinline__ unsigned short f2bf(float f) {
    unsigned int u = __float_as_uint(f);
    unsigned int r = (u + 0x7fffu + ((u >> 16) & 1u)) >> 16;
    return (unsigned short)r;
}
__device__ __forceinline__ float bf2f(unsigned short h) {
    return __uint_as_float(((unsigned int)h) << 16);
}

// async global->LDS, 16B per lane; lds dest = wave-uniform base + lane*16
__device__ __forceinline__ void gl_lds16(const unsigned short* g, unsigned short* l) {
    __builtin_amdgcn_global_load_lds(
        (const __attribute__((address_space(1))) unsigned int*)(g),
        (__attribute__((address_space(3))) unsigned int*)(l),
        16, 0, 0);
}

// ---------------------------------------------------------------------------
__global__ void build_rowptr(const int* __restrict__ src, int E, int n_nodes,
                             int* __restrict__ row_ptr) {
    int n = blockIdx.x * blockDim.x + threadIdx.x;
    if (n > n_nodes) return;
    int lo = 0, hi = E;
    while (lo < hi) {
        int mid = (lo + hi) >> 1;
        if (src[mid] < n) lo = mid + 1; else hi = mid;
    }
    row_ptr[n] = lo;
}

// ---------------------------------------------------------------------------
__global__ __launch_bounds__(256) void cast_bf16(
    const float* __restrict__ in, unsigned short* __restrict__ out, int total8) {
    int i = blockIdx.x * 256 + threadIdx.x;
    if (i >= total8) return;
    const float4* p = reinterpret_cast<const float4*>(in + (size_t)i * 8);
    float4 v0 = p[0], v1 = p[1];
    float vv[8] = {v0.x, v0.y, v0.z, v0.w, v1.x, v1.y, v1.z, v1.w};
    short8v o;
    #pragma unroll
    for (int q = 0; q < 8; ++q) o[q] = (short)f2bf(vv[q]);
    *reinterpret_cast<short8v*>(out + (size_t)i * 8) = o;
}

// ---------------------------------------------------------------------------
// W[h][f][d] f32  ->  Bt[(h*64+d)][F] bf16
// ---------------------------------------------------------------------------
__global__ void transpose_w_bf(const float* __restrict__ in,
                               unsigned short* __restrict__ outB,
                               int F, int total) {
    int idx = blockIdx.x * 256 + threadIdx.x;
    if (idx >= total) return;
    int d = idx & 63;
    int f = (idx >> 6) % F;
    int h = idx / (F << 6);
    outB[(size_t)((h << 6) + d) * F + f] = f2bf(in[idx]);
}

// ---------------------------------------------------------------------------
// C[M,N] = A(bf16)[M,K] @ B(bf16)[N,K]^T (+bias)
// Tile 128x256, BK=64, 512 threads = 8 waves (2x4, each 64x64).
// If f1out: fused per-head scores f1/f2 from the accumulator (wave's 64-col
// span == one head since BN, wc are 64-aligned).
// ---------------------------------------------------------------------------
__global__ __launch_bounds__(512) void gemm_bf16_fused(
    const unsigned short* __restrict__ A,
    const unsigned short* __restrict__ B,
    const float* __restrict__ bias,
    float* __restrict__ C, unsigned short* __restrict__ Cbf,
    const float* __restrict__ a_s, const float* __restrict__ a_d,
    float* __restrict__ f1out, float* __restrict__ f2out,
    int M, int K, int N)
{
    __shared__ unsigned short As[128][64];   // 16 KB
    __shared__ unsigned short Bs[256][64];   // 32 KB

    const int tid = threadIdx.x;
    const int bm = blockIdx.x * 128;
    const int bn = blockIdx.y * 256;
    const int wid = tid >> 6;
    const int lane = tid & 63;

    const int wr = (wid >> 2) * 64;      // 0/64
    const int wc = (wid & 3) * 64;       // 0/64/128/192
    const int fr = lane & 15;
    const int fks = (lane >> 4) * 8;

    const int a_r = lane >> 3;
    const int a_c = 8 * ((lane & 7) ^ a_r);

    float4v acc[4][4];
    #pragma unroll
    for (int m = 0; m < 4; ++m)
        #pragma unroll
        for (int n = 0; n < 4; ++n)
            acc[m][n] = (float4v){0.f, 0.f, 0.f, 0.f};

    for (int k0 = 0; k0 < K; k0 += 64) {
        // stage A (128 rows): 8 waves x 2 issues of 8 rows
        #pragma unroll
        for (int i = 0; i < 2; ++i) {
            int g = wid * 2 + i;
            int row = bm + g * 8 + a_r; if (row >= M) row = M - 1;
            gl_lds16(&A[(size_t)row * K + k0 + a_c], &As[g * 8][0]);
        }
        // stage B (256 rows): 8 waves x 4 issues
        #pragma unroll
        for (int i = 0; i < 4; ++i) {
            int g = wid * 4 + i;
            int row = bn + g * 8 + a_r; if (row >= N) row = N - 1;
            gl_lds16(&B[(size_t)row * K + k0 + a_c], &Bs[g * 8][0]);
        }
        __syncthreads();

        #pragma unroll
        for (int ks = 0; ks < 2; ++ks) {
            const int fko = ks * 32 + fks;
            short8v aF[4], bF[4];
            #pragma unroll
            for (int m = 0; m < 4; ++m) {
                int rr = wr + m * 16 + fr;
                aF[m] = *reinterpret_cast<const short8v*>(&As[rr][fko ^ ((rr & 7) * 8)]);
            }
            #pragma unroll
            for (int n = 0; n < 4; ++n) {
                int cc = wc + n * 16 + fr;
                bF[n] = *reinterpret_cast<const short8v*>(&Bs[cc][fko ^ ((cc & 7) * 8)]);
            }
            #pragma unroll
            for (int m = 0; m < 4; ++m)
                #pragma unroll
                for (int n = 0; n < 4; ++n)
                    acc[m][n] = __builtin_amdgcn_mfma_f32_16x16x32_bf16(aF[m], bF[n], acc[m][n], 0, 0, 0);
        }
        __syncthreads();
    }

    // ---- fused per-head scores: wave's 64 cols = one head ----
    if (f1out) {
        const int head = (bn + wc) >> 6;
        float asv[4], adv[4];
        #pragma unroll
        for (int n = 0; n < 4; ++n) {
            asv[n] = a_s[bn + wc + n * 16 + fr];   // flat [H*64] == [head][d]
            adv[n] = a_d[bn + wc + n * 16 + fr];
        }
        #pragma unroll
        for (int m = 0; m < 4; ++m) {
            #pragma unroll
            for (int r = 0; r < 4; ++r) {
                float ps = 0.f, pd = 0.f;
                #pragma unroll
                for (int n = 0; n < 4; ++n) {
                    ps += acc[m][n][r] * asv[n];
                    pd += acc[m][n][r] * adv[n];
                }
                #pragma unroll
                for (int mk = 1; mk <= 8; mk <<= 1) {
                    ps += __shfl_xor(ps, mk);
                    pd += __shfl_xor(pd, mk);
                }
                int row = bm + wr + m * 16 + (lane >> 4) * 4 + r;
                if (fr == 0 && row < M) {
                    f1out[(size_t)row * HEADS + head] = ps;
                    f2out[(size_t)row * HEADS + head] = pd;
                }
            }
        }
    }

    // ---- C write: C/D layout col=lane&15, row=(lane>>4)*4+r ----
    #pragma unroll
    for (int m = 0; m < 4; ++m) {
        int row0 = bm + wr + m * 16 + (lane >> 4) * 4;
        #pragma unroll
        for (int n = 0; n < 4; ++n) {
            int col = bn + wc + n * 16 + fr;
            if (col >= N) continue;
            float b = bias ? bias[col] : 0.f;
            #pragma unroll
            for (int r = 0; r < 4; ++r) {
                int row = row0 + r;
                if (row < M) {
                    if (Cbf) Cbf[(size_t)row * N + col] = f2bf(acc[m][n][r]);
                    else     C[(size_t)row * N + col] = acc[m][n][r] + b;
                }
            }
        }
    }
}

// ---------------------------------------------------------------------------
// gat_node, wave-per-node, no block barriers; bf16 in/out.
// ---------------------------------------------------------------------------
__global__ __launch_bounds__(256) void gat_node_wave(
    const unsigned short* __restrict__ Wh, const float* __restrict__ f1,
    const float* __restrict__ f2, const int* __restrict__ row_ptr,
    const int* __restrict__ dst, unsigned short* __restrict__ out, int n_nodes)
{
    __shared__ float s_p[4][DCAP][HEADS];   // 16 KB
    __shared__ int   s_dst[4][DCAP];        // 2 KB

    const int wv = threadIdx.x >> 6;
    const int lane = threadIdx.x & 63;
    const int n = blockIdx.x * 4 + wv;
    if (n >= n_nodes) return;

    const int lo = row_ptr[n], hi = row_ptr[n + 1];
    const int deg = hi - lo;

    const int h  = lane & 7;
    const int j8 = lane >> 3;
    const int hl = lane >> 3;
    const int dg = (lane & 7) * 8;
    const size_t base = (size_t)hl * DH + dg;

    const float f1h = f1[(size_t)n * HEADS + h];

    float m = -INFINITY;
    for (int b0 = 0; b0 < deg; b0 += 8) {
        int j = b0 + j8;
        float e = -INFINITY;
        if (j < deg) {
            int dn = dst[lo + j];
            e = f1h + f2[(size_t)dn * HEADS + h];
            e = e > 0.f ? e : ALPHA * e;
        }
        m = fmaxf(m, e);
    }
    #pragma unroll
    for (int mk = 8; mk <= 32; mk <<= 1) m = fmaxf(m, __shfl_xor(m, mk));

    float ssum = 0.f;
    float acc[8] = {0.f, 0.f, 0.f, 0.f, 0.f, 0.f, 0.f, 0.f};

    for (int c0 = 0; c0 < deg; c0 += DCAP) {
        int cn = min(DCAP, deg - c0);
        for (int b0 = 0; b0 < cn; b0 += 8) {
            int j = b0 + j8;
            float p = 0.f;
            if (j < cn) {
                int dn = dst[lo + c0 + j];
                float e = f1h + f2[(size_t)dn * HEADS + h];
                e = e > 0.f ? e : ALPHA * e;
                p = __expf(e - m);
                s_p[wv][j][h] = p;
                if (h == 0) s_dst[wv][j] = dn;
            }
            ssum += p;
        }
        asm volatile("s_waitcnt lgkmcnt(0)" ::: "memory");

        // ---- gather: 4-deep pipeline ----
        int j = 0;
        for (; j + 4 <= cn; j += 4) {
            int dn0 = s_dst[wv][j + 0];
            int dn1 = s_dst[wv][j + 1];
            int dn2 = s_dst[wv][j + 2];
            int dn3 = s_dst[wv][j + 3];
            float p0 = s_p[wv][j + 0][hl];
            float p1 = s_p[wv][j + 1][hl];
            float p2 = s_p[wv][j + 2][hl];
            float p3 = s_p[wv][j + 3][hl];
            uint4 u0 = *reinterpret_cast<const uint4*>(&Wh[(size_t)dn0 * HD + base]);
            uint4 u1 = *reinterpret_cast<const uint4*>(&Wh[(size_t)dn1 * HD + base]);
            uint4 u2 = *reinterpret_cast<const uint4*>(&Wh[(size_t)dn2 * HD + base]);
            uint4 u3 = *reinterpret_cast<const uint4*>(&Wh[(size_t)dn3 * HD + base]);
            unsigned int w0[4] = {u0.x, u0.y, u0.z, u0.w};
            unsigned int w1[4] = {u1.x, u1.y, u1.z, u1.w};
            unsigned int w2[4] = {u2.x, u2.y, u2.z, u2.w};
            unsigned int w3[4] = {u3.x, u3.y, u3.z, u3.w};
            #pragma unroll
            for (int q = 0; q < 4; ++q) {
                acc[2 * q]     += p0 * __uint_as_float(w0[q] << 16);
                acc[2 * q + 1] += p0 * __uint_as_float(w0[q] & 0xffff0000u);
                acc[2 * q]     += p1 * __uint_as_float(w1[q] << 16);
                acc[2 * q + 1] += p1 * __uint_as_float(w1[q] & 0xffff0000u);
                acc[2 * q]     += p2 * __uint_as_float(w2[q] << 16);
                acc[2 * q + 1] += p2 * __uint_as_float(w2[q] & 0xffff0000u);
                acc[2 * q]     += p3 * __uint_as_float(w3[q] << 16);
                acc[2 * q + 1] += p3 * __uint_as_float(w3[q] & 0xffff0000u);
            }
        }
        for (; j < cn; ++j) {
            int dn = s_dst[wv][j];
            float p = s_p[wv][j][hl];
            uint4 u = *reinterpret_cast<const uint4*>(&Wh[(size_t)dn * HD + base]);
            unsigned int uu[4] = {u.x, u.y, u.z, u.w};
            #pragma unroll
            for (int q = 0; q < 4; ++q) {
                acc[2 * q]     += p * __uint_as_float(uu[q] << 16);
                acc[2 * q + 1] += p * __uint_as_float(uu[q] & 0xffff0000u);
            }
        }
        asm volatile("s_waitcnt lgkmcnt(0)" ::: "memory");
    }

    #pragma unroll
    for (int mk = 8; mk <= 32; mk <<= 1) ssum += __shfl_xor(ssum, mk);
    float inv = 1.f / fmaxf(ssum, 1e-16f);
    float invg = __shfl(inv, hl);

    short8v o8;
    #pragma unroll
    for (int q = 0; q < 8; ++q) {
        float v = acc[q] * invg;
        v = v > 0.f ? v : expm1f(v);
        o8[q] = (short)f2bf(v);
    }
    *reinterpret_cast<short8v*>(&out[(size_t)n * HD + hl * DH + dg]) = o8;
}

// ---------------------------------------------------------------------------
extern "C" void kernel_launch(void* const* d_in, const int* in_sizes, int n_in,
                              void* d_out, int out_size, void* d_ws, size_t ws_size,
                              hipStream_t stream) {
    const float* x      = (const float*)d_in[0];
    const int*   e_src  = (const int*)d_in[1];
    const int*   e_dst  = (const int*)d_in[2];
    const float* W1     = (const float*)d_in[3];
    const float* a_src1 = (const float*)d_in[4];
    const float* a_dst1 = (const float*)d_in[5];
    const float* W2     = (const float*)d_in[6];
    const float* a_src2 = (const float*)d_in[7];
    const float* a_dst2 = (const float*)d_in[8];
    const float* lin_W  = (const float*)d_in[9];
    const float* lin_b  = (const float*)d_in[10];
    float* outp = (float*)d_out;

    const size_t NHD = (size_t)N_NODES * HD;       // 25.6M
    unsigned short* WhBf = (unsigned short*)d_ws;  // 51.2 MB
    unsigned short* hBf  = WhBf + NHD;             // 51.2 MB
    unsigned short* xBf  = hBf + NHD;              // 25.6 MB
    float* f1    = (float*)(xBf + (size_t)N_NODES * 256);
    float* f2    = f1 + (size_t)N_NODES * HEADS;
    int* rowptr  = (int*)(f2 + (size_t)N_NODES * HEADS);
    unsigned short* BtW1  = (unsigned short*)(rowptr + N_NODES + 64);
    unsigned short* BtW2  = BtW1 + (size_t)HD * 256;
    unsigned short* BtLin = BtW2 + (size_t)HD * HD;

    build_rowptr<<<(N_NODES + 256) / 256, 256, 0, stream>>>(e_src, N_EDGES, N_NODES, rowptr);
    cast_bf16<<<(N_NODES * 256 / 8 + 255) / 256, 256, 0, stream>>>(x, xBf, N_NODES * 256 / 8);
    transpose_w_bf<<<(HEADS * 256 * DH + 255) / 256, 256, 0, stream>>>(W1, BtW1, 256, HEADS * 256 * DH);
    transpose_w_bf<<<(HEADS * HD * DH + 255) / 256, 256, 0, stream>>>(W2, BtW2, HD, HEADS * HD * DH);
    transpose_w_bf<<<(HD * 64 + 255) / 256, 256, 0, stream>>>(lin_W, BtLin, HD, HD * 64);

    const int nwb = (N_NODES + 3) / 4;
    dim3 g1((N_NODES + 127) / 128, HD / 256);   // 391 x 2

    // layer 1: Wh + f1/f2 fused
    gemm_bf16_fused<<<g1, 512, 0, stream>>>(xBf, BtW1, nullptr, nullptr, WhBf,
                                            a_src1, a_dst1, f1, f2, N_NODES, 256, HD);
    gat_node_wave<<<nwb, 256, 0, stream>>>(WhBf, f1, f2, rowptr, e_dst, hBf, N_NODES);

    // layer 2
    gemm_bf16_fused<<<g1, 512, 0, stream>>>(hBf, BtW2, nullptr, nullptr, WhBf,
                                            a_src2, a_dst2, f1, f2, N_NODES, HD, HD);
    gat_node_wave<<<nwb, 256, 0, stream>>>(WhBf, f1, f2, rowptr, e_dst, hBf, N_NODES);

    // output: f32 + bias (scores path off)
    dim3 g3((N_NODES + 127) / 128, 1);
    gemm_bf16_fused<<<g3, 512, 0, stream>>>(hBf, BtLin, lin_b, outp, nullptr,
                                            nullptr, nullptr, nullptr, nullptr, N_NODES, HD, 64);
}

// Round 9
// 387.237 us; speedup vs baseline: 3.1023x; 1.0272x over previous
//
#include <hip/hip_runtime.h>
#include <hip/hip_bf16.h>
#include <math.h>

#define ALPHA 0.2f
#define N_NODES 50000
#define N_EDGES 800000
#define HEADS 8
#define DH 64
#define HD 512   // HEADS*DH
#define DCAP 128 // edges per softmax/gather chunk (per wave)

typedef __attribute__((ext_vector_type(8))) short short8v;
typedef __attribute__((ext_vector_type(4))) float float4v;

// round-to-nearest-even f32 -> bf16 bits
__device__ __forceinline__ unsigned short f2bf(float f) {
    unsigned int u = __float_as_uint(f);
    unsigned int r = (u + 0x7fffu + ((u >> 16) & 1u)) >> 16;
    return (unsigned short)r;
}
__device__ __forceinline__ float bf2f(unsigned short h) {
    return __uint_as_float(((unsigned int)h) << 16);
}

// async global->LDS, 16B per lane; lds dest = wave-uniform base + lane*16
__device__ __forceinline__ void gl_lds16(const unsigned short* g, unsigned short* l) {
    __builtin_amdgcn_global_load_lds(
        (const __attribute__((address_space(1))) unsigned int*)(g),
        (__attribute__((address_space(3))) unsigned int*)(l),
        16, 0, 0);
}

// ---------------------------------------------------------------------------
// Merged preprocessing: rowptr + x cast + 3 weight transposes (independent).
// ---------------------------------------------------------------------------
#define PPR0 50001                 // rowptr
#define PPR1 (PPR0 + 1600000)      // cast x (8 elems each)
#define PPR2 (PPR1 + 131072)       // W1 transpose (F=256)
#define PPR3 (PPR2 + 262144)       // W2 transpose (F=512)
#define PPR4 (PPR3 + 32768)        // lin transpose

__global__ __launch_bounds__(256) void preproc(
    const int* __restrict__ esrc, int* __restrict__ row_ptr,
    const float* __restrict__ x, unsigned short* __restrict__ xBf,
    const float* __restrict__ W1, unsigned short* __restrict__ BtW1,
    const float* __restrict__ W2, unsigned short* __restrict__ BtW2,
    const float* __restrict__ linW, unsigned short* __restrict__ BtLin)
{
    const int stride = gridDim.x * 256;
    for (int i = blockIdx.x * 256 + threadIdx.x; i < PPR4; i += stride) {
        if (i < PPR0) {
            int n = i;
            int lo = 0, hi = N_EDGES;
            while (lo < hi) {
                int mid = (lo + hi) >> 1;
                if (esrc[mid] < n) lo = mid + 1; else hi = mid;
            }
            row_ptr[n] = lo;
        } else if (i < PPR1) {
            int idx = i - PPR0;
            const float4* p = reinterpret_cast<const float4*>(x + (size_t)idx * 8);
            float4 v0 = p[0], v1 = p[1];
            float vv[8] = {v0.x, v0.y, v0.z, v0.w, v1.x, v1.y, v1.z, v1.w};
            short8v o;
            #pragma unroll
            for (int q = 0; q < 8; ++q) o[q] = (short)f2bf(vv[q]);
            *reinterpret_cast<short8v*>(xBf + (size_t)idx * 8) = o;
        } else if (i < PPR2) {
            int idx = i - PPR1;                 // W1: [h][f][d], F=256
            int d = idx & 63;
            int f = (idx >> 6) & 255;
            int h = idx >> 14;
            BtW1[(size_t)((h << 6) + d) * 256 + f] = f2bf(W1[idx]);
        } else if (i < PPR3) {
            int idx = i - PPR2;                 // W2: F=512
            int d = idx & 63;
            int f = (idx >> 6) & 511;
            int h = idx >> 15;
            BtW2[(size_t)((h << 6) + d) * 512 + f] = f2bf(W2[idx]);
        } else {
            int idx = i - PPR3;                 // lin_W: [512][64]
            int o = idx & 63;
            int k = idx >> 6;
            BtLin[(size_t)o * 512 + k] = f2bf(linW[idx]);
        }
    }
}

// ---------------------------------------------------------------------------
// C[M,N] = A(bf16)[M,K] @ B(bf16)[N,K]^T (+bias)
// Tile 128x256, BK=64, 512 threads = 8 waves (2x4, each 64x64).
// 1-D grid + bijective XCD swizzle; (m-block, col-block) paired so both
// col-blocks of one A-panel run adjacent on the same XCD (A L2-hit).
// If f1out: fused per-head scores from the accumulator.
// ---------------------------------------------------------------------------
__global__ __launch_bounds__(512) void gemm_bf16_fused(
    const unsigned short* __restrict__ A,
    const unsigned short* __restrict__ B,
    const float* __restrict__ bias,
    float* __restrict__ C, unsigned short* __restrict__ Cbf,
    const float* __restrict__ a_s, const float* __restrict__ a_d,
    float* __restrict__ f1out, float* __restrict__ f2out,
    int M, int K, int N, int ncol)
{
    __shared__ unsigned short As[128][64];   // 16 KB
    __shared__ unsigned short Bs[256][64];   // 32 KB

    // bijective XCD swizzle (8 XCDs), then pair-decompose
    const int nwg = gridDim.x;
    const int orig = blockIdx.x;
    const int qq = nwg >> 3, rr8 = nwg & 7;
    const int xcd = orig & 7, idx8 = orig >> 3;
    const int wgid = (xcd < rr8 ? xcd * (qq + 1) : rr8 * (qq + 1) + (xcd - rr8) * qq) + idx8;
    const int bm = (wgid / ncol) * 128;
    const int bn = (wgid % ncol) * 256;

    const int tid = threadIdx.x;
    const int wid = tid >> 6;
    const int lane = tid & 63;

    const int wr = (wid >> 2) * 64;      // 0/64
    const int wc = (wid & 3) * 64;       // 0/64/128/192
    const int fr = lane & 15;
    const int fks = (lane >> 4) * 8;

    const int a_r = lane >> 3;
    const int a_c = 8 * ((lane & 7) ^ a_r);

    float4v acc[4][4];
    #pragma unroll
    for (int m = 0; m < 4; ++m)
        #pragma unroll
        for (int n = 0; n < 4; ++n)
            acc[m][n] = (float4v){0.f, 0.f, 0.f, 0.f};

    for (int k0 = 0; k0 < K; k0 += 64) {
        #pragma unroll
        for (int i = 0; i < 2; ++i) {
            int g = wid * 2 + i;
            int row = bm + g * 8 + a_r; if (row >= M) row = M - 1;
            gl_lds16(&A[(size_t)row * K + k0 + a_c], &As[g * 8][0]);
        }
        #pragma unroll
        for (int i = 0; i < 4; ++i) {
            int g = wid * 4 + i;
            int row = bn + g * 8 + a_r; if (row >= N) row = N - 1;
            gl_lds16(&B[(size_t)row * K + k0 + a_c], &Bs[g * 8][0]);
        }
        __syncthreads();

        #pragma unroll
        for (int ks = 0; ks < 2; ++ks) {
            const int fko = ks * 32 + fks;
            short8v aF[4], bF[4];
            #pragma unroll
            for (int m = 0; m < 4; ++m) {
                int rw = wr + m * 16 + fr;
                aF[m] = *reinterpret_cast<const short8v*>(&As[rw][fko ^ ((rw & 7) * 8)]);
            }
            #pragma unroll
            for (int n = 0; n < 4; ++n) {
                int cc = wc + n * 16 + fr;
                bF[n] = *reinterpret_cast<const short8v*>(&Bs[cc][fko ^ ((cc & 7) * 8)]);
            }
            #pragma unroll
            for (int m = 0; m < 4; ++m)
                #pragma unroll
                for (int n = 0; n < 4; ++n)
                    acc[m][n] = __builtin_amdgcn_mfma_f32_16x16x32_bf16(aF[m], bF[n], acc[m][n], 0, 0, 0);
        }
        __syncthreads();
    }

    // ---- fused per-head scores: wave's 64 cols = one head ----
    if (f1out) {
        const int head = (bn + wc) >> 6;
        float asv[4], adv[4];
        #pragma unroll
        for (int n = 0; n < 4; ++n) {
            asv[n] = a_s[bn + wc + n * 16 + fr];
            adv[n] = a_d[bn + wc + n * 16 + fr];
        }
        #pragma unroll
        for (int m = 0; m < 4; ++m) {
            #pragma unroll
            for (int r = 0; r < 4; ++r) {
                float ps = 0.f, pd = 0.f;
                #pragma unroll
                for (int n = 0; n < 4; ++n) {
                    ps += acc[m][n][r] * asv[n];
                    pd += acc[m][n][r] * adv[n];
                }
                #pragma unroll
                for (int mk = 1; mk <= 8; mk <<= 1) {
                    ps += __shfl_xor(ps, mk);
                    pd += __shfl_xor(pd, mk);
                }
                int row = bm + wr + m * 16 + (lane >> 4) * 4 + r;
                if (fr == 0 && row < M) {
                    f1out[(size_t)row * HEADS + head] = ps;
                    f2out[(size_t)row * HEADS + head] = pd;
                }
            }
        }
    }

    // ---- C write: C/D layout col=lane&15, row=(lane>>4)*4+r ----
    #pragma unroll
    for (int m = 0; m < 4; ++m) {
        int row0 = bm + wr + m * 16 + (lane >> 4) * 4;
        #pragma unroll
        for (int n = 0; n < 4; ++n) {
            int col = bn + wc + n * 16 + fr;
            if (col >= N) continue;
            float b = bias ? bias[col] : 0.f;
            #pragma unroll
            for (int r = 0; r < 4; ++r) {
                int row = row0 + r;
                if (row < M) {
                    if (Cbf) Cbf[(size_t)row * N + col] = f2bf(acc[m][n][r]);
                    else     C[(size_t)row * N + col] = acc[m][n][r] + b;
                }
            }
        }
    }
}

// ---------------------------------------------------------------------------
// gat_node, wave-per-node, no block barriers; bf16 in/out.
// ---------------------------------------------------------------------------
__global__ __launch_bounds__(256) void gat_node_wave(
    const unsigned short* __restrict__ Wh, const float* __restrict__ f1,
    const float* __restrict__ f2, const int* __restrict__ row_ptr,
    const int* __restrict__ dst, unsigned short* __restrict__ out, int n_nodes)
{
    __shared__ float s_p[4][DCAP][HEADS];   // 16 KB
    __shared__ int   s_dst[4][DCAP];        // 2 KB

    const int wv = threadIdx.x >> 6;
    const int lane = threadIdx.x & 63;
    const int n = blockIdx.x * 4 + wv;
    if (n >= n_nodes) return;

    const int lo = row_ptr[n], hi = row_ptr[n + 1];
    const int deg = hi - lo;

    const int h  = lane & 7;
    const int j8 = lane >> 3;
    const int hl = lane >> 3;
    const int dg = (lane & 7) * 8;
    const size_t base = (size_t)hl * DH + dg;

    const float f1h = f1[(size_t)n * HEADS + h];

    float m = -INFINITY;
    for (int b0 = 0; b0 < deg; b0 += 8) {
        int j = b0 + j8;
        float e = -INFINITY;
        if (j < deg) {
            int dn = dst[lo + j];
            e = f1h + f2[(size_t)dn * HEADS + h];
            e = e > 0.f ? e : ALPHA * e;
        }
        m = fmaxf(m, e);
    }
    #pragma unroll
    for (int mk = 8; mk <= 32; mk <<= 1) m = fmaxf(m, __shfl_xor(m, mk));

    float ssum = 0.f;
    float acc[8] = {0.f, 0.f, 0.f, 0.f, 0.f, 0.f, 0.f, 0.f};

    for (int c0 = 0; c0 < deg; c0 += DCAP) {
        int cn = min(DCAP, deg - c0);
        for (int b0 = 0; b0 < cn; b0 += 8) {
            int j = b0 + j8;
            float p = 0.f;
            if (j < cn) {
                int dn = dst[lo + c0 + j];
                float e = f1h + f2[(size_t)dn * HEADS + h];
                e = e > 0.f ? e : ALPHA * e;
                p = __expf(e - m);
                s_p[wv][j][h] = p;
                if (h == 0) s_dst[wv][j] = dn;
            }
            ssum += p;
        }
        asm volatile("s_waitcnt lgkmcnt(0)" ::: "memory");

        // ---- gather: 4-deep pipeline ----
        int j = 0;
        for (; j + 4 <= cn; j += 4) {
            int dn0 = s_dst[wv][j + 0];
            int dn1 = s_dst[wv][j + 1];
            int dn2 = s_dst[wv][j + 2];
            int dn3 = s_dst[wv][j + 3];
            float p0 = s_p[wv][j + 0][hl];
            float p1 = s_p[wv][j + 1][hl];
            float p2 = s_p[wv][j + 2][hl];
            float p3 = s_p[wv][j + 3][hl];
            uint4 u0 = *reinterpret_cast<const uint4*>(&Wh[(size_t)dn0 * HD + base]);
            uint4 u1 = *reinterpret_cast<const uint4*>(&Wh[(size_t)dn1 * HD + base]);
            uint4 u2 = *reinterpret_cast<const uint4*>(&Wh[(size_t)dn2 * HD + base]);
            uint4 u3 = *reinterpret_cast<const uint4*>(&Wh[(size_t)dn3 * HD + base]);
            unsigned int w0[4] = {u0.x, u0.y, u0.z, u0.w};
            unsigned int w1[4] = {u1.x, u1.y, u1.z, u1.w};
            unsigned int w2[4] = {u2.x, u2.y, u2.z, u2.w};
            unsigned int w3[4] = {u3.x, u3.y, u3.z, u3.w};
            #pragma unroll
            for (int q = 0; q < 4; ++q) {
                acc[2 * q]     += p0 * __uint_as_float(w0[q] << 16);
                acc[2 * q + 1] += p0 * __uint_as_float(w0[q] & 0xffff0000u);
                acc[2 * q]     += p1 * __uint_as_float(w1[q] << 16);
                acc[2 * q + 1] += p1 * __uint_as_float(w1[q] & 0xffff0000u);
                acc[2 * q]     += p2 * __uint_as_float(w2[q] << 16);
                acc[2 * q + 1] += p2 * __uint_as_float(w2[q] & 0xffff0000u);
                acc[2 * q]     += p3 * __uint_as_float(w3[q] << 16);
                acc[2 * q + 1] += p3 * __uint_as_float(w3[q] & 0xffff0000u);
            }
        }
        for (; j < cn; ++j) {
            int dn = s_dst[wv][j];
            float p = s_p[wv][j][hl];
            uint4 u = *reinterpret_cast<const uint4*>(&Wh[(size_t)dn * HD + base]);
            unsigned int uu[4] = {u.x, u.y, u.z, u.w};
            #pragma unroll
            for (int q = 0; q < 4; ++q) {
                acc[2 * q]     += p * __uint_as_float(uu[q] << 16);
                acc[2 * q + 1] += p * __uint_as_float(uu[q] & 0xffff0000u);
            }
        }
        asm volatile("s_waitcnt lgkmcnt(0)" ::: "memory");
    }

    #pragma unroll
    for (int mk = 8; mk <= 32; mk <<= 1) ssum += __shfl_xor(ssum, mk);
    float inv = 1.f / fmaxf(ssum, 1e-16f);
    float invg = __shfl(inv, hl);

    short8v o8;
    #pragma unroll
    for (int q = 0; q < 8; ++q) {
        float v = acc[q] * invg;
        v = v > 0.f ? v : expm1f(v);
        o8[q] = (short)f2bf(v);
    }
    *reinterpret_cast<short8v*>(&out[(size_t)n * HD + hl * DH + dg]) = o8;
}

// ---------------------------------------------------------------------------
extern "C" void kernel_launch(void* const* d_in, const int* in_sizes, int n_in,
                              void* d_out, int out_size, void* d_ws, size_t ws_size,
                              hipStream_t stream) {
    const float* x      = (const float*)d_in[0];
    const int*   e_src  = (const int*)d_in[1];
    const int*   e_dst  = (const int*)d_in[2];
    const float* W1     = (const float*)d_in[3];
    const float* a_src1 = (const float*)d_in[4];
    const float* a_dst1 = (const float*)d_in[5];
    const float* W2     = (const float*)d_in[6];
    const float* a_src2 = (const float*)d_in[7];
    const float* a_dst2 = (const float*)d_in[8];
    const float* lin_W  = (const float*)d_in[9];
    const float* lin_b  = (const float*)d_in[10];
    float* outp = (float*)d_out;

    const size_t NHD = (size_t)N_NODES * HD;       // 25.6M
    unsigned short* WhBf = (unsigned short*)d_ws;  // 51.2 MB
    unsigned short* hBf  = WhBf + NHD;             // 51.2 MB
    unsigned short* xBf  = hBf + NHD;              // 25.6 MB
    float* f1    = (float*)(xBf + (size_t)N_NODES * 256);
    float* f2    = f1 + (size_t)N_NODES * HEADS;
    int* rowptr  = (int*)(f2 + (size_t)N_NODES * HEADS);
    unsigned short* BtW1  = (unsigned short*)(rowptr + N_NODES + 64);
    unsigned short* BtW2  = BtW1 + (size_t)HD * 256;
    unsigned short* BtLin = BtW2 + (size_t)HD * HD;

    preproc<<<2048, 256, 0, stream>>>(e_src, rowptr, x, xBf, W1, BtW1, W2, BtW2, lin_W, BtLin);

    const int nwb = (N_NODES + 3) / 4;
    const int nmb = (N_NODES + 127) / 128;   // 391

    // layer 1: Wh + f1/f2 fused (paired 1-D grid: 391*2)
    gemm_bf16_fused<<<nmb * 2, 512, 0, stream>>>(xBf, BtW1, nullptr, nullptr, WhBf,
                                                 a_src1, a_dst1, f1, f2, N_NODES, 256, HD, 2);
    gat_node_wave<<<nwb, 256, 0, stream>>>(WhBf, f1, f2, rowptr, e_dst, hBf, N_NODES);

    // layer 2
    gemm_bf16_fused<<<nmb * 2, 512, 0, stream>>>(hBf, BtW2, nullptr, nullptr, WhBf,
                                                 a_src2, a_dst2, f1, f2, N_NODES, HD, HD, 2);
    gat_node_wave<<<nwb, 256, 0, stream>>>(WhBf, f1, f2, rowptr, e_dst, hBf, N_NODES);

    // output: f32 + bias (scores path off), single col-block
    gemm_bf16_fused<<<nmb, 512, 0, stream>>>(hBf, BtLin, lin_b, outp, nullptr,
                                             nullptr, nullptr, nullptr, nullptr, N_NODES, HD, 64, 1);
}